// Round 1
// baseline (304.738 us; speedup 1.0000x reference)
//
#include <hip/hip_runtime.h>
#include <math.h>

// ---------------------------------------------------------------------------
// Problem: B=4, N=2048, D=256.
// Key exact simplifications (see analysis):
//  * intra+inter == 1  -> attention = softmax_j(leaky_relu(s1_i + s2_j)), no masks
//  * rank-1 + monotone -> h_prime via sorted-s2 prefix sums (O(N D), exact)
//  * evt / k_base / w_i / w_o folded into matvecs; only 3 big GEMMs remain
// ---------------------------------------------------------------------------

namespace {
constexpr int B = 4, N = 2048, D = 256;
constexpr float ALPHA = 0.2f;
constexpr float INVS  = 0.0625f;   // 1/sqrt(256)

// ws offsets (float elements)
constexpr size_t OFF_H     = 0;                       // (B,N,D)
constexpr size_t OFF_HP    = 2097152;                 // h_prime
constexpr size_t OFF_UE    = 4194304;                 // u_emo
constexpr size_t OFF_UA    = 6291456;                 // u_act
constexpr size_t OFF_PPOS  = 8388608;                 // (B,N+1,D) prefix, later reused as Ve
constexpr size_t OFF_PNEG  = 10486784;                // (B,N+1,D) prefix, later reused as Va
constexpr size_t OFF_VE    = OFF_PPOS;
constexpr size_t OFF_VA    = OFF_PNEG;
constexpr size_t OFF_S1    = 12584960;                // (B,N)
constexpr size_t OFF_S2    = OFF_S1 + 8192;
constexpr size_t OFF_SV    = OFF_S2 + 8192;           // sorted s2
constexpr size_t OFF_SIDX  = OFF_SV + 8192;           // permutation (int)
constexpr size_t OFF_WP    = OFF_SIDX + 8192;         // e^{s2} sorted
constexpr size_t OFF_WN    = OFF_WP + 8192;           // e^{a s2} sorted
constexpr size_t OFF_ZP    = OFF_WN + 8192;           // (B,N+1) scalar prefix
constexpr size_t OFF_ZN    = OFF_ZP + 8196;
constexpr size_t OFF_PARTP = OFF_ZN + 8196;           // (B,32,D) chunk partials
constexpr size_t OFF_PARTN = OFF_PARTP + 32768;
constexpr size_t OFF_OFFP  = OFF_PARTN + 32768;
constexpr size_t OFF_OFFN  = OFF_OFFP + 32768;
constexpr size_t OFF_LE    = OFF_OFFN + 32768;        // emo logits
constexpr size_t OFF_LA    = OFF_LE + 8192;           // act logits
constexpr size_t OFF_SET   = OFF_LA + 8192;
constexpr size_t KQE = OFF_SET + 0;      // kW@q per batch (B,256)
constexpr size_t WQE = OFF_SET + 1024;
constexpr size_t KQA = OFF_SET + 2048;
constexpr size_t WQA = OFF_SET + 3072;
constexpr size_t QCE = OFF_SET + 4096;   // q + vb + wb
constexpr size_t QCA = OFF_SET + 5120;
constexpr size_t CA2 = OFF_SET + 6144;   // csk_W @ a2 (256)
constexpr size_t CEc = OFF_SET + 6400;   // q.(kb+wb) per batch
constexpr size_t CAc = OFF_SET + 6404;
constexpr size_t C2c = OFF_SET + 6408;   // 2*csk_b.a2
}

__device__ inline float wave_sum(float v) {
#pragma unroll
  for (int off = 32; off > 0; off >>= 1) v += __shfl_xor(v, off, 64);
  return v;
}

__device__ inline float rowdot256(const float* __restrict__ row, const float* q) {
  float s = 0.f;
#pragma unroll 8
  for (int k4 = 0; k4 < 64; ++k4) {
    float4 w = reinterpret_cast<const float4*>(row)[k4];
    s += w.x * q[4*k4] + w.y * q[4*k4+1] + w.z * q[4*k4+2] + w.w * q[4*k4+3];
  }
  return s;
}

// --- setup: per-batch target vectors, folded matvecs --------------------------
__global__ __launch_bounds__(256) void k_setup(
    const float* __restrict__ inp, const float* __restrict__ emo,
    const float* __restrict__ a, const float* __restrict__ cskW,
    const float* __restrict__ cskb,
    const float* __restrict__ eW, const float* __restrict__ eb,
    const float* __restrict__ aW, const float* __restrict__ ab,
    const int* __restrict__ cl, float* __restrict__ ws)
{
  int b = blockIdx.x, d = threadIdx.x;
  __shared__ float x_e[D], x_a[D], red[D];
  int t = cl[b] - 1;
  float tv = inp[((size_t)b*N + t)*D + d];
  x_e[d] = tv + emo[((size_t)b*N + t)*D + d];
  x_a[d] = tv;
  __syncthreads();
  // q = x @ qW + qb  (qW = lin_W[1]), coalesced over d
  float qe = eb[D + d];
  float qa = ab[D + d];
  for (int k = 0; k < D; ++k) {
    qe += x_e[k] * eW[(size_t)(D + k)*D + d];
    qa += x_a[k] * aW[(size_t)(D + k)*D + d];
  }
  __syncthreads();
  x_e[d] = qe; x_a[d] = qa;
  __syncthreads();
  // kq = kW@q (lin_W[2]), wq = wW@q (lin_W[0])
  ws[KQE + b*D + d] = rowdot256(&eW[(size_t)(2*D + d)*D], x_e);
  ws[WQE + b*D + d] = rowdot256(&eW[(size_t)(0*D + d)*D], x_e);
  ws[KQA + b*D + d] = rowdot256(&aW[(size_t)(2*D + d)*D], x_a);
  ws[WQA + b*D + d] = rowdot256(&aW[(size_t)(0*D + d)*D], x_a);
  // qc = q + vb + wb  (lin_b[3], lin_b[0])
  ws[QCE + b*D + d] = qe + eb[3*D + d] + eb[0*D + d];
  ws[QCA + b*D + d] = qa + ab[3*D + d] + ab[0*D + d];
  // c = q.(kb+wb)
  red[d] = qe * (eb[2*D + d] + eb[0*D + d]);
  __syncthreads();
  for (int s = 128; s > 0; s >>= 1) { if (d < s) red[d] += red[d+s]; __syncthreads(); }
  if (d == 0) ws[CEc + b] = red[0];
  __syncthreads();
  red[d] = qa * (ab[2*D + d] + ab[0*D + d]);
  __syncthreads();
  for (int s = 128; s > 0; s >>= 1) { if (d < s) red[d] += red[d+s]; __syncthreads(); }
  if (d == 0) ws[CAc + b] = red[0];
  __syncthreads();
  if (b == 0) {
    // ca2 = csk_W @ a2 ; c2 = 2 * csk_b . a2
    red[d] = a[D + d];
    __syncthreads();
    ws[CA2 + d] = rowdot256(&cskW[(size_t)d*D], red);
    __syncthreads();
    x_e[d] = cskb[d] * a[D + d];
    __syncthreads();
    for (int s = 128; s > 0; s >>= 1) { if (d < s) x_e[d] += x_e[d+s]; __syncthreads(); }
    if (d == 0) ws[C2c] = 2.0f * x_e[0];
  }
}

// --- generic f32 GEMM: C(8192,256) = A1(8192,K)@B1(K,256) [+ A2@B2] ----------
__global__ __launch_bounds__(256) void k_gemm(
    const float* __restrict__ A1, const float* __restrict__ B1,
    const float* __restrict__ A2, const float* __restrict__ B2,
    float* __restrict__ C, int K)
{
  __shared__ float As[16][64];
  __shared__ float Bs[16][64];
  const int tid = threadIdx.x;
  const int tx = tid & 15, ty = tid >> 4;
  const int m0 = blockIdx.x * 64, n0 = blockIdx.y * 64;
  const int lr = tid >> 2, lk = (tid & 3) << 2;
  const int bk = tid >> 4, bc = (tid & 15) << 2;
  float acc[4][4] = {{0.f}};
  for (int src = 0; src < 2; ++src) {
    const float* A  = src ? A2 : A1;
    const float* Bm = src ? B2 : B1;
    if (!A) break;
    for (int k0 = 0; k0 < K; k0 += 16) {
      float4 av = *reinterpret_cast<const float4*>(&A[(size_t)(m0 + lr)*K + k0 + lk]);
      float4 bv = *reinterpret_cast<const float4*>(&Bm[(size_t)(k0 + bk)*D + n0 + bc]);
      __syncthreads();
      As[lk+0][lr] = av.x; As[lk+1][lr] = av.y; As[lk+2][lr] = av.z; As[lk+3][lr] = av.w;
      *reinterpret_cast<float4*>(&Bs[bk][bc]) = bv;
      __syncthreads();
#pragma unroll
      for (int k = 0; k < 16; ++k) {
        float a0 = As[k][ty*4+0], a1 = As[k][ty*4+1], a2 = As[k][ty*4+2], a3 = As[k][ty*4+3];
        float b0 = Bs[k][tx*4+0], b1 = Bs[k][tx*4+1], b2 = Bs[k][tx*4+2], b3 = Bs[k][tx*4+3];
        acc[0][0] += a0*b0; acc[0][1] += a0*b1; acc[0][2] += a0*b2; acc[0][3] += a0*b3;
        acc[1][0] += a1*b0; acc[1][1] += a1*b1; acc[1][2] += a1*b2; acc[1][3] += a1*b3;
        acc[2][0] += a2*b0; acc[2][1] += a2*b1; acc[2][2] += a2*b2; acc[2][3] += a2*b3;
        acc[3][0] += a3*b0; acc[3][1] += a3*b1; acc[3][2] += a3*b2; acc[3][3] += a3*b3;
      }
    }
  }
#pragma unroll
  for (int i = 0; i < 4; ++i)
#pragma unroll
    for (int j = 0; j < 4; ++j)
      C[(size_t)(m0 + ty*4 + i)*D + n0 + tx*4 + j] = acc[i][j];
}

// --- u = tim*icsk + (1-tim)*ocsk for both measures ---------------------------
__global__ __launch_bounds__(256) void k_u(
    const float* __restrict__ ei, const float* __restrict__ eo,
    const float* __restrict__ ai, const float* __restrict__ ao,
    const int* __restrict__ cl, const int* __restrict__ intra,
    float* __restrict__ ws)
{
  size_t g = (size_t)blockIdx.x*256 + threadIdx.x;
  size_t base = g << 2;
  int b = (int)(base >> 19);              // N*D = 2^19
  int n = (int)((base >> 8) & (N - 1));
  int t = cl[b] - 1;
  float tm = (float)intra[(size_t)b*N*N + (size_t)t*N + n];
  float om = 1.0f - tm;
  float4 vei = *(const float4*)&ei[base];
  float4 veo = *(const float4*)&eo[base];
  float4 vai = *(const float4*)&ai[base];
  float4 vao = *(const float4*)&ao[base];
  float4 ue, ua;
  ue.x = tm*vei.x + om*veo.x; ue.y = tm*vei.y + om*veo.y;
  ue.z = tm*vei.z + om*veo.z; ue.w = tm*vei.w + om*veo.w;
  ua.x = tm*vai.x + om*vao.x; ua.y = tm*vai.y + om*vao.y;
  ua.z = tm*vai.z + om*vao.z; ua.w = tm*vai.w + om*vao.w;
  *(float4*)&ws[OFF_UE + base] = ue;
  *(float4*)&ws[OFF_UA + base] = ua;
}

// --- s1 = h.a1 ; s2 = h.a2 + (bef+aft).ca2 + c2 ------------------------------
__global__ __launch_bounds__(256) void k_s12(
    const float* __restrict__ bef, const float* __restrict__ aft,
    const float* __restrict__ a, float* __restrict__ ws)
{
  int wid  = (int)(((size_t)blockIdx.x*256 + threadIdx.x) >> 6);
  int lane = threadIdx.x & 63;
  int d0 = lane << 2;
  float4 a1 = *(const float4*)&a[d0];
  float4 a2 = *(const float4*)&a[D + d0];
  float4 cv = *(const float4*)&ws[CA2 + d0];
  float c2  = ws[C2c];
  for (int rr = 0; rr < 4; ++rr) {
    int row = wid*4 + rr;
    float4 h4 = *(const float4*)&ws[OFF_H + (size_t)row*D + d0];
    float4 b4 = *(const float4*)&bef[(size_t)row*D + d0];
    float4 f4 = *(const float4*)&aft[(size_t)row*D + d0];
    float s1 = h4.x*a1.x + h4.y*a1.y + h4.z*a1.z + h4.w*a1.w;
    float s2 = h4.x*a2.x + h4.y*a2.y + h4.z*a2.z + h4.w*a2.w
             + (b4.x+f4.x)*cv.x + (b4.y+f4.y)*cv.y
             + (b4.z+f4.z)*cv.z + (b4.w+f4.w)*cv.w;
    s1 = wave_sum(s1); s2 = wave_sum(s2);
    if (lane == 0) { ws[OFF_S1 + row] = s1; ws[OFF_S2 + row] = s2 + c2; }
  }
}

// --- bitonic sort of s2 per batch + scalar prefix sums of e^{s2}, e^{a s2} ---
__global__ __launch_bounds__(1024) void k_sort(float* __restrict__ ws)
{
  int b = blockIdx.x, t = threadIdx.x;
  __shared__ float skey[N];
  __shared__ int   sidxl[N];
  skey[t]        = ws[OFF_S2 + (size_t)b*N + t];
  skey[t + 1024] = ws[OFF_S2 + (size_t)b*N + t + 1024];
  sidxl[t] = t; sidxl[t + 1024] = t + 1024;
  __syncthreads();
  for (int k = 2; k <= N; k <<= 1)
    for (int j = k >> 1; j > 0; j >>= 1) {
      for (int h = 0; h < 2; ++h) {
        int i = t + h*1024;
        int l = i ^ j;
        if (l > i) {
          float ki = skey[i], kl = skey[l];
          bool up = ((i & k) == 0);
          if (up ? (ki > kl) : (ki < kl)) {
            skey[i] = kl; skey[l] = ki;
            int tmp = sidxl[i]; sidxl[i] = sidxl[l]; sidxl[l] = tmp;
          }
        }
      }
      __syncthreads();
    }
  ws[OFF_SV + (size_t)b*N + t]        = skey[t];
  ws[OFF_SV + (size_t)b*N + t + 1024] = skey[t + 1024];
  int* wsi = (int*)ws;
  wsi[OFF_SIDX + (size_t)b*N + t]        = sidxl[t];
  wsi[OFF_SIDX + (size_t)b*N + t + 1024] = sidxl[t + 1024];
  ws[OFF_WP + (size_t)b*N + t]        = expf(skey[t]);
  ws[OFF_WP + (size_t)b*N + t + 1024] = expf(skey[t + 1024]);
  ws[OFF_WN + (size_t)b*N + t]        = expf(ALPHA*skey[t]);
  ws[OFF_WN + (size_t)b*N + t + 1024] = expf(ALPHA*skey[t + 1024]);
  __syncthreads();
  float* buf = (float*)sidxl;
  for (int pass = 0; pass < 2; ++pass) {
    float m = pass ? ALPHA : 1.0f;
    buf[t]        = expf(m*skey[t]);
    buf[t + 1024] = expf(m*skey[t + 1024]);
    __syncthreads();
    for (int off = 1; off < N; off <<= 1) {
      float v0 = (t >= off)        ? buf[t - off]        : 0.f;
      float v1 = (t + 1024 >= off) ? buf[t + 1024 - off] : 0.f;
      __syncthreads();
      buf[t] += v0; buf[t + 1024] += v1;
      __syncthreads();
    }
    size_t zo = (pass ? OFF_ZN : OFF_ZP) + (size_t)b*(N+1);
    if (t == 0) ws[zo] = 0.f;
    ws[zo + t + 1]    = buf[t];
    ws[zo + t + 1025] = buf[t + 1024];
    __syncthreads();
  }
}

// --- vector prefix sums over sorted order: 3-pass ----------------------------
__global__ __launch_bounds__(256) void k_p1(float* __restrict__ ws)
{
  int c = blockIdx.x, b = blockIdx.y, d = threadIdx.x;
  const int*   sidx = (const int*)ws + OFF_SIDX + (size_t)b*N;
  const float* wp = ws + OFF_WP + (size_t)b*N;
  const float* wn = ws + OFF_WN + (size_t)b*N;
  const float* h  = ws + OFF_H + (size_t)b*N*D;
  float ap = 0.f, an = 0.f;
  for (int r = c*64; r < c*64 + 64; ++r) {
    float hv = h[(size_t)sidx[r]*D + d];
    ap += wp[r]*hv; an += wn[r]*hv;
  }
  ws[OFF_PARTP + ((size_t)b*32 + c)*D + d] = ap;
  ws[OFF_PARTN + ((size_t)b*32 + c)*D + d] = an;
}

__global__ __launch_bounds__(256) void k_p2(float* __restrict__ ws)
{
  int b = blockIdx.x, d = threadIdx.x;
  float ap = 0.f, an = 0.f;
  for (int c = 0; c < 32; ++c) {
    size_t o = ((size_t)b*32 + c)*D + d;
    float tp = ws[OFF_PARTP + o], tn = ws[OFF_PARTN + o];
    ws[OFF_OFFP + o] = ap; ws[OFF_OFFN + o] = an;
    ap += tp; an += tn;
  }
}

__global__ __launch_bounds__(256) void k_p3(float* __restrict__ ws)
{
  int c = blockIdx.x, b = blockIdx.y, d = threadIdx.x;
  const int*   sidx = (const int*)ws + OFF_SIDX + (size_t)b*N;
  const float* wp = ws + OFF_WP + (size_t)b*N;
  const float* wn = ws + OFF_WN + (size_t)b*N;
  const float* h  = ws + OFF_H + (size_t)b*N*D;
  float ap = ws[OFF_OFFP + ((size_t)b*32 + c)*D + d];
  float an = ws[OFF_OFFN + ((size_t)b*32 + c)*D + d];
  for (int r = c*64; r < c*64 + 64; ++r) {
    ws[OFF_PPOS + ((size_t)b*(N+1) + r)*D + d] = ap;
    ws[OFF_PNEG + ((size_t)b*(N+1) + r)*D + d] = an;
    float hv = h[(size_t)sidx[r]*D + d];
    ap += wp[r]*hv; an += wn[r]*hv;
  }
  if (c == 31) {
    ws[OFF_PPOS + ((size_t)b*(N+1) + N)*D + d] = ap;
    ws[OFF_PNEG + ((size_t)b*(N+1) + N)*D + d] = an;
  }
}

// --- h_prime[i] = (e^{s1} Suf_pos(r_i) + e^{a s1} Pre_neg(r_i)) / denom ------
__global__ __launch_bounds__(256) void k_hprime(float* __restrict__ ws)
{
  int blk = blockIdx.x, b = blockIdx.y, d = threadIdx.x;
  __shared__ float svl[N];
  for (int r = d; r < N; r += 256) svl[r] = ws[OFF_SV + (size_t)b*N + r];
  __syncthreads();
  float totp = ws[OFF_PPOS + ((size_t)b*(N+1) + N)*D + d];
  float zpT  = ws[OFF_ZP + (size_t)b*(N+1) + N];
  for (int ii = 0; ii < 64; ++ii) {
    int i = blk*64 + ii;
    float s1i = ws[OFF_S1 + (size_t)b*N + i];
    float th = -s1i;
    int lo = 0, hi = N;
    while (lo < hi) { int mid = (lo + hi) >> 1; if (svl[mid] <= th) lo = mid + 1; else hi = mid; }
    int r = lo;
    float ep = expf(s1i), en = expf(ALPHA*s1i);
    float pp = ws[OFF_PPOS + ((size_t)b*(N+1) + r)*D + d];
    float pn = ws[OFF_PNEG + ((size_t)b*(N+1) + r)*D + d];
    float zp = ws[OFF_ZP + (size_t)b*(N+1) + r];
    float zn = ws[OFF_ZN + (size_t)b*(N+1) + r];
    float den = ep*(zpT - zp) + en*zn;
    float num = ep*(totp - pp) + en*pn;
    ws[OFF_HP + ((size_t)b*N + i)*D + d] = num / den;
  }
}

// --- logits: inv*(h'.kq + u.wq + c) ------------------------------------------
__global__ __launch_bounds__(256) void k_logits(float* __restrict__ ws)
{
  int wid  = (int)(((size_t)blockIdx.x*256 + threadIdx.x) >> 6);
  int lane = threadIdx.x & 63;
  int d0 = lane << 2;
  int row0 = wid*4;
  int b = row0 >> 11;
  float4 kqe = *(const float4*)&ws[KQE + (size_t)b*D + d0];
  float4 wqe = *(const float4*)&ws[WQE + (size_t)b*D + d0];
  float4 kqa = *(const float4*)&ws[KQA + (size_t)b*D + d0];
  float4 wqa = *(const float4*)&ws[WQA + (size_t)b*D + d0];
  float ce = ws[CEc + b], ca = ws[CAc + b];
  for (int rr = 0; rr < 4; ++rr) {
    int row = row0 + rr;
    float4 hp = *(const float4*)&ws[OFF_HP + (size_t)row*D + d0];
    float4 ue = *(const float4*)&ws[OFF_UE + (size_t)row*D + d0];
    float4 ua = *(const float4*)&ws[OFF_UA + (size_t)row*D + d0];
    float se = hp.x*kqe.x + hp.y*kqe.y + hp.z*kqe.z + hp.w*kqe.w
             + ue.x*wqe.x + ue.y*wqe.y + ue.z*wqe.z + ue.w*wqe.w;
    float sa = hp.x*kqa.x + hp.y*kqa.y + hp.z*kqa.z + hp.w*kqa.w
             + ua.x*wqa.x + ua.y*wqa.y + ua.z*wqa.z + ua.w*wqa.w;
    se = wave_sum(se); sa = wave_sum(sa);
    if (lane == 0) {
      ws[OFF_LE + row] = (se + ce) * INVS;
      ws[OFF_LA + row] = (sa + ca) * INVS;
    }
  }
}

// --- probs softmax over N, writes directly to d_out --------------------------
__global__ __launch_bounds__(1024) void k_softmax(const float* __restrict__ ws,
                                                  float* __restrict__ out)
{
  int b = blockIdx.x, t = threadIdx.x;
  __shared__ float red[1024];
  for (int m = 0; m < 2; ++m) {
    const float* l = ws + (m ? OFF_LA : OFF_LE) + (size_t)b*N;
    float* p = out + (size_t)B*N*D + (size_t)m*B*N + (size_t)b*N;
    float v0 = l[t], v1 = l[t + 1024];
    red[t] = fmaxf(v0, v1);
    __syncthreads();
    for (int s = 512; s > 0; s >>= 1) { if (t < s) red[t] = fmaxf(red[t], red[t+s]); __syncthreads(); }
    float mx = red[0];
    __syncthreads();
    float e0 = expf(v0 - mx), e1 = expf(v1 - mx);
    red[t] = e0 + e1;
    __syncthreads();
    for (int s = 512; s > 0; s >>= 1) { if (t < s) red[t] += red[t+s]; __syncthreads(); }
    float inv = 1.0f / red[0];
    __syncthreads();
    p[t] = e0 * inv; p[t + 1024] = e1 * inv;
    __syncthreads();
  }
}

// --- final: out = relu(h' + inp + pe*(qce+Ve) + pa*(qca+Va)) ------------------
__global__ __launch_bounds__(256) void k_final(
    const float* __restrict__ inp, const float* __restrict__ ws,
    float* __restrict__ out)
{
  size_t g = (size_t)blockIdx.x*256 + threadIdx.x;
  size_t base = g << 2;
  int b  = (int)(base >> 19);
  int n  = (int)((base >> 8) & (N - 1));
  int d0 = (int)(base & (D - 1));
  float pe = out[(size_t)B*N*D + (size_t)b*N + n];
  float pa = out[(size_t)B*N*D + (size_t)B*N + (size_t)b*N + n];
  float4 hp = *(const float4*)&ws[OFF_HP + base];
  float4 iv = *(const float4*)&inp[base];
  float4 ve = *(const float4*)&ws[OFF_VE + base];
  float4 va = *(const float4*)&ws[OFF_VA + base];
  float4 qe = *(const float4*)&ws[QCE + (size_t)b*D + d0];
  float4 qa = *(const float4*)&ws[QCA + (size_t)b*D + d0];
  float4 o;
  o.x = hp.x + iv.x + pe*(qe.x + ve.x) + pa*(qa.x + va.x);
  o.y = hp.y + iv.y + pe*(qe.y + ve.y) + pa*(qa.y + va.y);
  o.z = hp.z + iv.z + pe*(qe.z + ve.z) + pa*(qa.z + va.z);
  o.w = hp.w + iv.w + pe*(qe.w + ve.w) + pa*(qa.w + va.w);
  o.x = fmaxf(o.x, 0.f); o.y = fmaxf(o.y, 0.f);
  o.z = fmaxf(o.z, 0.f); o.w = fmaxf(o.w, 0.f);
  *(float4*)&out[base] = o;
}

extern "C" void kernel_launch(void* const* d_in, const int* in_sizes, int n_in,
                              void* d_out, int out_size, void* d_ws, size_t ws_size,
                              hipStream_t stream) {
  const float* inp  = (const float*)d_in[0];
  const float* emo  = (const float*)d_in[1];
  const float* bef  = (const float*)d_in[2];
  const float* aft  = (const float*)d_in[3];
  const float* ei   = (const float*)d_in[4];
  const float* eo   = (const float*)d_in[5];
  const float* ii   = (const float*)d_in[6];
  const float* io   = (const float*)d_in[7];
  const float* W    = (const float*)d_in[8];
  const float* a    = (const float*)d_in[9];
  const float* cskW = (const float*)d_in[10];
  const float* cskb = (const float*)d_in[11];
  const float* eW   = (const float*)d_in[12];
  const float* eb   = (const float*)d_in[13];
  const float* aW   = (const float*)d_in[14];
  const float* ab   = (const float*)d_in[15];
  const int*   cl   = (const int*)d_in[16];
  const int*   intra= (const int*)d_in[17];
  float* ws  = (float*)d_ws;
  float* out = (float*)d_out;

  k_setup<<<B, D, 0, stream>>>(inp, emo, a, cskW, cskb, eW, eb, aW, ab, cl, ws);
  k_gemm<<<dim3(128, 4), 256, 0, stream>>>(inp, W, nullptr, nullptr, ws + OFF_H, 256);
  k_u<<<2048, 256, 0, stream>>>(ei, eo, ii, io, cl, intra, ws);
  k_s12<<<512, 256, 0, stream>>>(bef, aft, a, ws);
  k_sort<<<B, 1024, 0, stream>>>(ws);
  k_p1<<<dim3(32, B), 256, 0, stream>>>(ws);
  k_p2<<<B, 256, 0, stream>>>(ws);
  k_p3<<<dim3(32, B), 256, 0, stream>>>(ws);
  k_hprime<<<dim3(32, B), 256, 0, stream>>>(ws);
  k_gemm<<<dim3(128, 4), 256, 0, stream>>>(ws + OFF_HP, eW + 3*65536, ws + OFF_UE, eW,
                                           ws + OFF_VE, 256);
  k_gemm<<<dim3(128, 4), 256, 0, stream>>>(ws + OFF_HP, aW + 3*65536, ws + OFF_UA, aW,
                                           ws + OFF_VA, 256);
  k_logits<<<512, 256, 0, stream>>>(ws);
  k_softmax<<<B, 1024, 0, stream>>>(ws, out);
  k_final<<<2048, 256, 0, stream>>>(inp, ws, out);
}

// Round 2
// 241.828 us; speedup vs baseline: 1.2601x; 1.2601x over previous
//
#include <hip/hip_runtime.h>
#include <math.h>

// ---------------------------------------------------------------------------
// Problem: B=4, N=2048, D=256.
// Key exact simplifications:
//  * intra+inter == 1  -> attention = softmax_j(leaky_relu(s1_i + s2_j)), no masks
//  * rank-1 + monotone -> h_prime via sorted-s2 prefix sums (O(N D), exact)
//  * evt / k_base / w_i / w_o folded into matvecs; only 3 big GEMMs remain
// R1: k_hprime split into k_rank (per-row binary search + coeffs) and
//     k_hprime2 (pure coalesced gather, 1024 blocks). Was 73us latency-bound.
// ---------------------------------------------------------------------------

namespace {
constexpr int B = 4, N = 2048, D = 256;
constexpr float ALPHA = 0.2f;
constexpr float INVS  = 0.0625f;   // 1/sqrt(256)

// ws offsets (float elements)
constexpr size_t OFF_H     = 0;                       // (B,N,D)
constexpr size_t OFF_HP    = 2097152;                 // h_prime
constexpr size_t OFF_UE    = 4194304;                 // u_emo
constexpr size_t OFF_UA    = 6291456;                 // u_act
constexpr size_t OFF_PPOS  = 8388608;                 // (B,N+1,D) prefix, later reused as Ve
constexpr size_t OFF_PNEG  = 10486784;                // (B,N+1,D) prefix, later reused as Va
constexpr size_t OFF_VE    = OFF_PPOS;
constexpr size_t OFF_VA    = OFF_PNEG;
constexpr size_t OFF_S1    = 12584960;                // (B,N)
constexpr size_t OFF_S2    = OFF_S1 + 8192;
constexpr size_t OFF_SV    = OFF_S2 + 8192;           // sorted s2
constexpr size_t OFF_SIDX  = OFF_SV + 8192;           // permutation (int)
constexpr size_t OFF_WP    = OFF_SIDX + 8192;         // e^{s2} sorted
constexpr size_t OFF_WN    = OFF_WP + 8192;           // e^{a s2} sorted
constexpr size_t OFF_ZP    = OFF_WN + 8192;           // (B,N+1) scalar prefix
constexpr size_t OFF_ZN    = OFF_ZP + 8196;
constexpr size_t OFF_PARTP = OFF_ZN + 8196;           // (B,32,D) chunk partials
constexpr size_t OFF_PARTN = OFF_PARTP + 32768;
constexpr size_t OFF_OFFP  = OFF_PARTN + 32768;
constexpr size_t OFF_OFFN  = OFF_OFFP + 32768;
constexpr size_t OFF_LE    = OFF_OFFN + 32768;        // emo logits
constexpr size_t OFF_LA    = OFF_LE + 8192;           // act logits
constexpr size_t OFF_SET   = OFF_LA + 8192;
constexpr size_t KQE = OFF_SET + 0;      // kW@q per batch (B,256)
constexpr size_t WQE = OFF_SET + 1024;
constexpr size_t KQA = OFF_SET + 2048;
constexpr size_t WQA = OFF_SET + 3072;
constexpr size_t QCE = OFF_SET + 4096;   // q + vb + wb
constexpr size_t QCA = OFF_SET + 5120;
constexpr size_t CA2 = OFF_SET + 6144;   // csk_W @ a2 (256)
constexpr size_t CEc = OFF_SET + 6400;   // q.(kb+wb) per batch
constexpr size_t CAc = OFF_SET + 6404;
constexpr size_t C2c = OFF_SET + 6408;   // 2*csk_b.a2
// R1: per-row rank + folded coefficients
constexpr size_t OFF_RNK   = OFF_SET + 8192;          // (B,N) int
constexpr size_t OFF_C0    = OFF_RNK + 8192;          // ep/den
constexpr size_t OFF_C1    = OFF_C0 + 8192;           // en/den
}

__device__ inline float wave_sum(float v) {
#pragma unroll
  for (int off = 32; off > 0; off >>= 1) v += __shfl_xor(v, off, 64);
  return v;
}

__device__ inline float rowdot256(const float* __restrict__ row, const float* q) {
  float s = 0.f;
#pragma unroll 8
  for (int k4 = 0; k4 < 64; ++k4) {
    float4 w = reinterpret_cast<const float4*>(row)[k4];
    s += w.x * q[4*k4] + w.y * q[4*k4+1] + w.z * q[4*k4+2] + w.w * q[4*k4+3];
  }
  return s;
}

// --- setup: per-batch target vectors, folded matvecs --------------------------
__global__ __launch_bounds__(256) void k_setup(
    const float* __restrict__ inp, const float* __restrict__ emo,
    const float* __restrict__ a, const float* __restrict__ cskW,
    const float* __restrict__ cskb,
    const float* __restrict__ eW, const float* __restrict__ eb,
    const float* __restrict__ aW, const float* __restrict__ ab,
    const int* __restrict__ cl, float* __restrict__ ws)
{
  int b = blockIdx.x, d = threadIdx.x;
  __shared__ float x_e[D], x_a[D], red[D];
  int t = cl[b] - 1;
  float tv = inp[((size_t)b*N + t)*D + d];
  x_e[d] = tv + emo[((size_t)b*N + t)*D + d];
  x_a[d] = tv;
  __syncthreads();
  // q = x @ qW + qb  (qW = lin_W[1]), coalesced over d
  float qe = eb[D + d];
  float qa = ab[D + d];
  for (int k = 0; k < D; ++k) {
    qe += x_e[k] * eW[(size_t)(D + k)*D + d];
    qa += x_a[k] * aW[(size_t)(D + k)*D + d];
  }
  __syncthreads();
  x_e[d] = qe; x_a[d] = qa;
  __syncthreads();
  // kq = kW@q (lin_W[2]), wq = wW@q (lin_W[0])
  ws[KQE + b*D + d] = rowdot256(&eW[(size_t)(2*D + d)*D], x_e);
  ws[WQE + b*D + d] = rowdot256(&eW[(size_t)(0*D + d)*D], x_e);
  ws[KQA + b*D + d] = rowdot256(&aW[(size_t)(2*D + d)*D], x_a);
  ws[WQA + b*D + d] = rowdot256(&aW[(size_t)(0*D + d)*D], x_a);
  // qc = q + vb + wb  (lin_b[3], lin_b[0])
  ws[QCE + b*D + d] = qe + eb[3*D + d] + eb[0*D + d];
  ws[QCA + b*D + d] = qa + ab[3*D + d] + ab[0*D + d];
  // c = q.(kb+wb)
  red[d] = qe * (eb[2*D + d] + eb[0*D + d]);
  __syncthreads();
  for (int s = 128; s > 0; s >>= 1) { if (d < s) red[d] += red[d+s]; __syncthreads(); }
  if (d == 0) ws[CEc + b] = red[0];
  __syncthreads();
  red[d] = qa * (ab[2*D + d] + ab[0*D + d]);
  __syncthreads();
  for (int s = 128; s > 0; s >>= 1) { if (d < s) red[d] += red[d+s]; __syncthreads(); }
  if (d == 0) ws[CAc + b] = red[0];
  __syncthreads();
  if (b == 0) {
    // ca2 = csk_W @ a2 ; c2 = 2 * csk_b . a2
    red[d] = a[D + d];
    __syncthreads();
    ws[CA2 + d] = rowdot256(&cskW[(size_t)d*D], red);
    __syncthreads();
    x_e[d] = cskb[d] * a[D + d];
    __syncthreads();
    for (int s = 128; s > 0; s >>= 1) { if (d < s) x_e[d] += x_e[d+s]; __syncthreads(); }
    if (d == 0) ws[C2c] = 2.0f * x_e[0];
  }
}

// --- generic f32 GEMM: C(8192,256) = A1(8192,K)@B1(K,256) [+ A2@B2] ----------
__global__ __launch_bounds__(256) void k_gemm(
    const float* __restrict__ A1, const float* __restrict__ B1,
    const float* __restrict__ A2, const float* __restrict__ B2,
    float* __restrict__ C, int K)
{
  __shared__ float As[16][64];
  __shared__ float Bs[16][64];
  const int tid = threadIdx.x;
  const int tx = tid & 15, ty = tid >> 4;
  const int m0 = blockIdx.x * 64, n0 = blockIdx.y * 64;
  const int lr = tid >> 2, lk = (tid & 3) << 2;
  const int bk = tid >> 4, bc = (tid & 15) << 2;
  float acc[4][4] = {{0.f}};
  for (int src = 0; src < 2; ++src) {
    const float* A  = src ? A2 : A1;
    const float* Bm = src ? B2 : B1;
    if (!A) break;
    for (int k0 = 0; k0 < K; k0 += 16) {
      float4 av = *reinterpret_cast<const float4*>(&A[(size_t)(m0 + lr)*K + k0 + lk]);
      float4 bv = *reinterpret_cast<const float4*>(&Bm[(size_t)(k0 + bk)*D + n0 + bc]);
      __syncthreads();
      As[lk+0][lr] = av.x; As[lk+1][lr] = av.y; As[lk+2][lr] = av.z; As[lk+3][lr] = av.w;
      *reinterpret_cast<float4*>(&Bs[bk][bc]) = bv;
      __syncthreads();
#pragma unroll
      for (int k = 0; k < 16; ++k) {
        float a0 = As[k][ty*4+0], a1 = As[k][ty*4+1], a2 = As[k][ty*4+2], a3 = As[k][ty*4+3];
        float b0 = Bs[k][tx*4+0], b1 = Bs[k][tx*4+1], b2 = Bs[k][tx*4+2], b3 = Bs[k][tx*4+3];
        acc[0][0] += a0*b0; acc[0][1] += a0*b1; acc[0][2] += a0*b2; acc[0][3] += a0*b3;
        acc[1][0] += a1*b0; acc[1][1] += a1*b1; acc[1][2] += a1*b2; acc[1][3] += a1*b3;
        acc[2][0] += a2*b0; acc[2][1] += a2*b1; acc[2][2] += a2*b2; acc[2][3] += a2*b3;
        acc[3][0] += a3*b0; acc[3][1] += a3*b1; acc[3][2] += a3*b2; acc[3][3] += a3*b3;
      }
    }
  }
#pragma unroll
  for (int i = 0; i < 4; ++i)
#pragma unroll
    for (int j = 0; j < 4; ++j)
      C[(size_t)(m0 + ty*4 + i)*D + n0 + tx*4 + j] = acc[i][j];
}

// --- u = tim*icsk + (1-tim)*ocsk for both measures ---------------------------
__global__ __launch_bounds__(256) void k_u(
    const float* __restrict__ ei, const float* __restrict__ eo,
    const float* __restrict__ ai, const float* __restrict__ ao,
    const int* __restrict__ cl, const int* __restrict__ intra,
    float* __restrict__ ws)
{
  size_t g = (size_t)blockIdx.x*256 + threadIdx.x;
  size_t base = g << 2;
  int b = (int)(base >> 19);              // N*D = 2^19
  int n = (int)((base >> 8) & (N - 1));
  int t = cl[b] - 1;
  float tm = (float)intra[(size_t)b*N*N + (size_t)t*N + n];
  float om = 1.0f - tm;
  float4 vei = *(const float4*)&ei[base];
  float4 veo = *(const float4*)&eo[base];
  float4 vai = *(const float4*)&ai[base];
  float4 vao = *(const float4*)&ao[base];
  float4 ue, ua;
  ue.x = tm*vei.x + om*veo.x; ue.y = tm*vei.y + om*veo.y;
  ue.z = tm*vei.z + om*veo.z; ue.w = tm*vei.w + om*veo.w;
  ua.x = tm*vai.x + om*vao.x; ua.y = tm*vai.y + om*vao.y;
  ua.z = tm*vai.z + om*vao.z; ua.w = tm*vai.w + om*vao.w;
  *(float4*)&ws[OFF_UE + base] = ue;
  *(float4*)&ws[OFF_UA + base] = ua;
}

// --- s1 = h.a1 ; s2 = h.a2 + (bef+aft).ca2 + c2 ------------------------------
__global__ __launch_bounds__(256) void k_s12(
    const float* __restrict__ bef, const float* __restrict__ aft,
    const float* __restrict__ a, float* __restrict__ ws)
{
  int wid  = (int)(((size_t)blockIdx.x*256 + threadIdx.x) >> 6);
  int lane = threadIdx.x & 63;
  int d0 = lane << 2;
  float4 a1 = *(const float4*)&a[d0];
  float4 a2 = *(const float4*)&a[D + d0];
  float4 cv = *(const float4*)&ws[CA2 + d0];
  float c2  = ws[C2c];
  for (int rr = 0; rr < 4; ++rr) {
    int row = wid*4 + rr;
    float4 h4 = *(const float4*)&ws[OFF_H + (size_t)row*D + d0];
    float4 b4 = *(const float4*)&bef[(size_t)row*D + d0];
    float4 f4 = *(const float4*)&aft[(size_t)row*D + d0];
    float s1 = h4.x*a1.x + h4.y*a1.y + h4.z*a1.z + h4.w*a1.w;
    float s2 = h4.x*a2.x + h4.y*a2.y + h4.z*a2.z + h4.w*a2.w
             + (b4.x+f4.x)*cv.x + (b4.y+f4.y)*cv.y
             + (b4.z+f4.z)*cv.z + (b4.w+f4.w)*cv.w;
    s1 = wave_sum(s1); s2 = wave_sum(s2);
    if (lane == 0) { ws[OFF_S1 + row] = s1; ws[OFF_S2 + row] = s2 + c2; }
  }
}

// --- bitonic sort of s2 per batch + scalar prefix sums of e^{s2}, e^{a s2} ---
__global__ __launch_bounds__(1024) void k_sort(float* __restrict__ ws)
{
  int b = blockIdx.x, t = threadIdx.x;
  __shared__ float skey[N];
  __shared__ int   sidxl[N];
  skey[t]        = ws[OFF_S2 + (size_t)b*N + t];
  skey[t + 1024] = ws[OFF_S2 + (size_t)b*N + t + 1024];
  sidxl[t] = t; sidxl[t + 1024] = t + 1024;
  __syncthreads();
  for (int k = 2; k <= N; k <<= 1)
    for (int j = k >> 1; j > 0; j >>= 1) {
      for (int h = 0; h < 2; ++h) {
        int i = t + h*1024;
        int l = i ^ j;
        if (l > i) {
          float ki = skey[i], kl = skey[l];
          bool up = ((i & k) == 0);
          if (up ? (ki > kl) : (ki < kl)) {
            skey[i] = kl; skey[l] = ki;
            int tmp = sidxl[i]; sidxl[i] = sidxl[l]; sidxl[l] = tmp;
          }
        }
      }
      __syncthreads();
    }
  ws[OFF_SV + (size_t)b*N + t]        = skey[t];
  ws[OFF_SV + (size_t)b*N + t + 1024] = skey[t + 1024];
  int* wsi = (int*)ws;
  wsi[OFF_SIDX + (size_t)b*N + t]        = sidxl[t];
  wsi[OFF_SIDX + (size_t)b*N + t + 1024] = sidxl[t + 1024];
  ws[OFF_WP + (size_t)b*N + t]        = expf(skey[t]);
  ws[OFF_WP + (size_t)b*N + t + 1024] = expf(skey[t + 1024]);
  ws[OFF_WN + (size_t)b*N + t]        = expf(ALPHA*skey[t]);
  ws[OFF_WN + (size_t)b*N + t + 1024] = expf(ALPHA*skey[t + 1024]);
  __syncthreads();
  float* buf = (float*)sidxl;
  for (int pass = 0; pass < 2; ++pass) {
    float m = pass ? ALPHA : 1.0f;
    buf[t]        = expf(m*skey[t]);
    buf[t + 1024] = expf(m*skey[t + 1024]);
    __syncthreads();
    for (int off = 1; off < N; off <<= 1) {
      float v0 = (t >= off)        ? buf[t - off]        : 0.f;
      float v1 = (t + 1024 >= off) ? buf[t + 1024 - off] : 0.f;
      __syncthreads();
      buf[t] += v0; buf[t + 1024] += v1;
      __syncthreads();
    }
    size_t zo = (pass ? OFF_ZN : OFF_ZP) + (size_t)b*(N+1);
    if (t == 0) ws[zo] = 0.f;
    ws[zo + t + 1]    = buf[t];
    ws[zo + t + 1025] = buf[t + 1024];
    __syncthreads();
  }
}

// --- vector prefix sums over sorted order: 3-pass ----------------------------
__global__ __launch_bounds__(256) void k_p1(float* __restrict__ ws)
{
  int c = blockIdx.x, b = blockIdx.y, d = threadIdx.x;
  const int*   sidx = (const int*)ws + OFF_SIDX + (size_t)b*N;
  const float* wp = ws + OFF_WP + (size_t)b*N;
  const float* wn = ws + OFF_WN + (size_t)b*N;
  const float* h  = ws + OFF_H + (size_t)b*N*D;
  float ap = 0.f, an = 0.f;
  for (int r = c*64; r < c*64 + 64; ++r) {
    float hv = h[(size_t)sidx[r]*D + d];
    ap += wp[r]*hv; an += wn[r]*hv;
  }
  ws[OFF_PARTP + ((size_t)b*32 + c)*D + d] = ap;
  ws[OFF_PARTN + ((size_t)b*32 + c)*D + d] = an;
}

__global__ __launch_bounds__(256) void k_p2(float* __restrict__ ws)
{
  int b = blockIdx.x, d = threadIdx.x;
  float ap = 0.f, an = 0.f;
  for (int c = 0; c < 32; ++c) {
    size_t o = ((size_t)b*32 + c)*D + d;
    float tp = ws[OFF_PARTP + o], tn = ws[OFF_PARTN + o];
    ws[OFF_OFFP + o] = ap; ws[OFF_OFFN + o] = an;
    ap += tp; an += tn;
  }
}

__global__ __launch_bounds__(256) void k_p3(float* __restrict__ ws)
{
  int c = blockIdx.x, b = blockIdx.y, d = threadIdx.x;
  const int*   sidx = (const int*)ws + OFF_SIDX + (size_t)b*N;
  const float* wp = ws + OFF_WP + (size_t)b*N;
  const float* wn = ws + OFF_WN + (size_t)b*N;
  const float* h  = ws + OFF_H + (size_t)b*N*D;
  float ap = ws[OFF_OFFP + ((size_t)b*32 + c)*D + d];
  float an = ws[OFF_OFFN + ((size_t)b*32 + c)*D + d];
  for (int r = c*64; r < c*64 + 64; ++r) {
    ws[OFF_PPOS + ((size_t)b*(N+1) + r)*D + d] = ap;
    ws[OFF_PNEG + ((size_t)b*(N+1) + r)*D + d] = an;
    float hv = h[(size_t)sidx[r]*D + d];
    ap += wp[r]*hv; an += wn[r]*hv;
  }
  if (c == 31) {
    ws[OFF_PPOS + ((size_t)b*(N+1) + N)*D + d] = ap;
    ws[OFF_PNEG + ((size_t)b*(N+1) + N)*D + d] = an;
  }
}

// --- R1: per-row rank + folded softmax coefficients --------------------------
__global__ __launch_bounds__(256) void k_rank(float* __restrict__ ws)
{
  int b = blockIdx.y;
  int i = blockIdx.x * 256 + threadIdx.x;
  __shared__ float sv[N];
  for (int r = threadIdx.x; r < N; r += 256) sv[r] = ws[OFF_SV + (size_t)b*N + r];
  __syncthreads();
  float s1i = ws[OFF_S1 + (size_t)b*N + i];
  float th = -s1i;
  int lo = 0, hi = N;
  while (lo < hi) { int mid = (lo + hi) >> 1; if (sv[mid] <= th) lo = mid + 1; else hi = mid; }
  int r = lo;
  float ep = expf(s1i), en = expf(ALPHA*s1i);
  float zp  = ws[OFF_ZP + (size_t)b*(N+1) + r];
  float zn  = ws[OFF_ZN + (size_t)b*(N+1) + r];
  float zpT = ws[OFF_ZP + (size_t)b*(N+1) + N];
  float den = ep*(zpT - zp) + en*zn;
  ((int*)ws)[OFF_RNK + (size_t)b*N + i] = r;
  ws[OFF_C0 + (size_t)b*N + i] = ep/den;
  ws[OFF_C1 + (size_t)b*N + i] = en/den;
}

// --- R1: h_prime gather: hp[i,d] = c0*(totp[d]-pp[r,d]) + c1*pn[r,d] ---------
__global__ __launch_bounds__(256) void k_hprime2(float* __restrict__ ws)
{
  int b = blockIdx.y, d = threadIdx.x;
  int i0 = blockIdx.x * 8;
  float totp = ws[OFF_PPOS + ((size_t)b*(N+1) + N)*D + d];
#pragma unroll
  for (int ii = 0; ii < 8; ++ii) {
    int i = i0 + ii;
    int   r  = ((const int*)ws)[OFF_RNK + (size_t)b*N + i];
    float c0 = ws[OFF_C0 + (size_t)b*N + i];
    float c1 = ws[OFF_C1 + (size_t)b*N + i];
    float pp = ws[OFF_PPOS + ((size_t)b*(N+1) + r)*D + d];
    float pn = ws[OFF_PNEG + ((size_t)b*(N+1) + r)*D + d];
    ws[OFF_HP + ((size_t)b*N + i)*D + d] = c0*(totp - pp) + c1*pn;
  }
}

// --- logits: inv*(h'.kq + u.wq + c) ------------------------------------------
__global__ __launch_bounds__(256) void k_logits(float* __restrict__ ws)
{
  int wid  = (int)(((size_t)blockIdx.x*256 + threadIdx.x) >> 6);
  int lane = threadIdx.x & 63;
  int d0 = lane << 2;
  int row0 = wid*4;
  int b = row0 >> 11;
  float4 kqe = *(const float4*)&ws[KQE + (size_t)b*D + d0];
  float4 wqe = *(const float4*)&ws[WQE + (size_t)b*D + d0];
  float4 kqa = *(const float4*)&ws[KQA + (size_t)b*D + d0];
  float4 wqa = *(const float4*)&ws[WQA + (size_t)b*D + d0];
  float ce = ws[CEc + b], ca = ws[CAc + b];
  for (int rr = 0; rr < 4; ++rr) {
    int row = row0 + rr;
    float4 hp = *(const float4*)&ws[OFF_HP + (size_t)row*D + d0];
    float4 ue = *(const float4*)&ws[OFF_UE + (size_t)row*D + d0];
    float4 ua = *(const float4*)&ws[OFF_UA + (size_t)row*D + d0];
    float se = hp.x*kqe.x + hp.y*kqe.y + hp.z*kqe.z + hp.w*kqe.w
             + ue.x*wqe.x + ue.y*wqe.y + ue.z*wqe.z + ue.w*wqe.w;
    float sa = hp.x*kqa.x + hp.y*kqa.y + hp.z*kqa.z + hp.w*kqa.w
             + ua.x*wqa.x + ua.y*wqa.y + ua.z*wqa.z + ua.w*wqa.w;
    se = wave_sum(se); sa = wave_sum(sa);
    if (lane == 0) {
      ws[OFF_LE + row] = (se + ce) * INVS;
      ws[OFF_LA + row] = (sa + ca) * INVS;
    }
  }
}

// --- probs softmax over N, writes directly to d_out --------------------------
__global__ __launch_bounds__(1024) void k_softmax(const float* __restrict__ ws,
                                                  float* __restrict__ out)
{
  int b = blockIdx.x, t = threadIdx.x;
  __shared__ float red[1024];
  for (int m = 0; m < 2; ++m) {
    const float* l = ws + (m ? OFF_LA : OFF_LE) + (size_t)b*N;
    float* p = out + (size_t)B*N*D + (size_t)m*B*N + (size_t)b*N;
    float v0 = l[t], v1 = l[t + 1024];
    red[t] = fmaxf(v0, v1);
    __syncthreads();
    for (int s = 512; s > 0; s >>= 1) { if (t < s) red[t] = fmaxf(red[t], red[t+s]); __syncthreads(); }
    float mx = red[0];
    __syncthreads();
    float e0 = expf(v0 - mx), e1 = expf(v1 - mx);
    red[t] = e0 + e1;
    __syncthreads();
    for (int s = 512; s > 0; s >>= 1) { if (t < s) red[t] += red[t+s]; __syncthreads(); }
    float inv = 1.0f / red[0];
    __syncthreads();
    p[t] = e0 * inv; p[t + 1024] = e1 * inv;
    __syncthreads();
  }
}

// --- final: out = relu(h' + inp + pe*(qce+Ve) + pa*(qca+Va)) ------------------
__global__ __launch_bounds__(256) void k_final(
    const float* __restrict__ inp, const float* __restrict__ ws,
    float* __restrict__ out)
{
  size_t g = (size_t)blockIdx.x*256 + threadIdx.x;
  size_t base = g << 2;
  int b  = (int)(base >> 19);
  int n  = (int)((base >> 8) & (N - 1));
  int d0 = (int)(base & (D - 1));
  float pe = out[(size_t)B*N*D + (size_t)b*N + n];
  float pa = out[(size_t)B*N*D + (size_t)B*N + (size_t)b*N + n];
  float4 hp = *(const float4*)&ws[OFF_HP + base];
  float4 iv = *(const float4*)&inp[base];
  float4 ve = *(const float4*)&ws[OFF_VE + base];
  float4 va = *(const float4*)&ws[OFF_VA + base];
  float4 qe = *(const float4*)&ws[QCE + (size_t)b*D + d0];
  float4 qa = *(const float4*)&ws[QCA + (size_t)b*D + d0];
  float4 o;
  o.x = hp.x + iv.x + pe*(qe.x + ve.x) + pa*(qa.x + va.x);
  o.y = hp.y + iv.y + pe*(qe.y + ve.y) + pa*(qa.y + va.y);
  o.z = hp.z + iv.z + pe*(qe.z + ve.z) + pa*(qa.z + va.z);
  o.w = hp.w + iv.w + pe*(qe.w + ve.w) + pa*(qa.w + va.w);
  o.x = fmaxf(o.x, 0.f); o.y = fmaxf(o.y, 0.f);
  o.z = fmaxf(o.z, 0.f); o.w = fmaxf(o.w, 0.f);
  *(float4*)&out[base] = o;
}

extern "C" void kernel_launch(void* const* d_in, const int* in_sizes, int n_in,
                              void* d_out, int out_size, void* d_ws, size_t ws_size,
                              hipStream_t stream) {
  const float* inp  = (const float*)d_in[0];
  const float* emo  = (const float*)d_in[1];
  const float* bef  = (const float*)d_in[2];
  const float* aft  = (const float*)d_in[3];
  const float* ei   = (const float*)d_in[4];
  const float* eo   = (const float*)d_in[5];
  const float* ii   = (const float*)d_in[6];
  const float* io   = (const float*)d_in[7];
  const float* W    = (const float*)d_in[8];
  const float* a    = (const float*)d_in[9];
  const float* cskW = (const float*)d_in[10];
  const float* cskb = (const float*)d_in[11];
  const float* eW   = (const float*)d_in[12];
  const float* eb   = (const float*)d_in[13];
  const float* aW   = (const float*)d_in[14];
  const float* ab   = (const float*)d_in[15];
  const int*   cl   = (const int*)d_in[16];
  const int*   intra= (const int*)d_in[17];
  float* ws  = (float*)d_ws;
  float* out = (float*)d_out;

  k_setup<<<B, D, 0, stream>>>(inp, emo, a, cskW, cskb, eW, eb, aW, ab, cl, ws);
  k_gemm<<<dim3(128, 4), 256, 0, stream>>>(inp, W, nullptr, nullptr, ws + OFF_H, 256);
  k_u<<<2048, 256, 0, stream>>>(ei, eo, ii, io, cl, intra, ws);
  k_s12<<<512, 256, 0, stream>>>(bef, aft, a, ws);
  k_sort<<<B, 1024, 0, stream>>>(ws);
  k_rank<<<dim3(8, B), 256, 0, stream>>>(ws);
  k_p1<<<dim3(32, B), 256, 0, stream>>>(ws);
  k_p2<<<B, 256, 0, stream>>>(ws);
  k_p3<<<dim3(32, B), 256, 0, stream>>>(ws);
  k_hprime2<<<dim3(256, B), 256, 0, stream>>>(ws);
  k_gemm<<<dim3(128, 4), 256, 0, stream>>>(ws + OFF_HP, eW + 3*65536, ws + OFF_UE, eW,
                                           ws + OFF_VE, 256);
  k_gemm<<<dim3(128, 4), 256, 0, stream>>>(ws + OFF_HP, aW + 3*65536, ws + OFF_UA, aW,
                                           ws + OFF_VA, 256);
  k_logits<<<512, 256, 0, stream>>>(ws);
  k_softmax<<<B, 1024, 0, stream>>>(ws, out);
  k_final<<<2048, 256, 0, stream>>>(inp, ws, out);
}

// Round 3
// 199.628 us; speedup vs baseline: 1.5265x; 1.2114x over previous
//
#include <hip/hip_runtime.h>
#include <math.h>

// ---------------------------------------------------------------------------
// Problem: B=4, N=2048, D=256.
// Key exact simplifications:
//  * intra+inter == 1  -> attention = softmax_j(leaky_relu(s1_i + s2_j)), no masks
//  * rank-1 + monotone -> h_prime via sorted-s2 prefix sums (O(N D), exact)
//  * evt / k_base / w_i / w_o folded into matvecs; only 3 big GEMMs remain
// R1: k_hprime split into k_rank + k_hprime2 (was 73us latency-bound).
// R2: k_setup (64us, 4 blocks, latency-bound) split into k_qpart (split-k,
//     coalesced, batch-amortized) + k_qfinish + k_rowdots (wave-per-row).
// ---------------------------------------------------------------------------

namespace {
constexpr int B = 4, N = 2048, D = 256;
constexpr float ALPHA = 0.2f;
constexpr float INVS  = 0.0625f;   // 1/sqrt(256)

// ws offsets (float elements)
constexpr size_t OFF_H     = 0;                       // (B,N,D)
constexpr size_t OFF_HP    = 2097152;                 // h_prime
constexpr size_t OFF_UE    = 4194304;                 // u_emo
constexpr size_t OFF_UA    = 6291456;                 // u_act
constexpr size_t OFF_PPOS  = 8388608;                 // (B,N+1,D) prefix, later reused as Ve
constexpr size_t OFF_PNEG  = 10486784;                // (B,N+1,D) prefix, later reused as Va
constexpr size_t OFF_VE    = OFF_PPOS;
constexpr size_t OFF_VA    = OFF_PNEG;
constexpr size_t OFF_S1    = 12584960;                // (B,N)
constexpr size_t OFF_S2    = OFF_S1 + 8192;
constexpr size_t OFF_SV    = OFF_S2 + 8192;           // sorted s2
constexpr size_t OFF_SIDX  = OFF_SV + 8192;           // permutation (int)
constexpr size_t OFF_WP    = OFF_SIDX + 8192;         // e^{s2} sorted
constexpr size_t OFF_WN    = OFF_WP + 8192;           // e^{a s2} sorted
constexpr size_t OFF_ZP    = OFF_WN + 8192;           // (B,N+1) scalar prefix
constexpr size_t OFF_ZN    = OFF_ZP + 8196;
constexpr size_t OFF_PARTP = OFF_ZN + 8196;           // (B,32,D) chunk partials
constexpr size_t OFF_PARTN = OFF_PARTP + 32768;
constexpr size_t OFF_OFFP  = OFF_PARTN + 32768;
constexpr size_t OFF_OFFN  = OFF_OFFP + 32768;
constexpr size_t OFF_LE    = OFF_OFFN + 32768;        // emo logits
constexpr size_t OFF_LA    = OFF_LE + 8192;           // act logits
constexpr size_t OFF_SET   = OFF_LA + 8192;
constexpr size_t KQE = OFF_SET + 0;      // kW@q per batch (B,256)
constexpr size_t WQE = OFF_SET + 1024;
constexpr size_t KQA = OFF_SET + 2048;
constexpr size_t WQA = OFF_SET + 3072;
constexpr size_t QCE = OFF_SET + 4096;   // q + vb + wb
constexpr size_t QCA = OFF_SET + 5120;
constexpr size_t CA2 = OFF_SET + 6144;   // csk_W @ a2 (256)
constexpr size_t CEc = OFF_SET + 6400;   // q.(kb+wb) per batch
constexpr size_t CAc = OFF_SET + 6404;
constexpr size_t C2c = OFF_SET + 6408;   // 2*csk_b.a2
// R1: per-row rank + folded coefficients
constexpr size_t OFF_RNK   = OFF_SET + 8192;          // (B,N) int
constexpr size_t OFF_C0    = OFF_RNK + 8192;          // ep/den
constexpr size_t OFF_C1    = OFF_C0 + 8192;           // en/den
// R2: setup scratch
constexpr size_t OFF_PARTQ = OFF_C1 + 8192;           // [m2][c16][b4][256]
constexpr size_t OFF_QE    = OFF_PARTQ + 32768;       // (B,256)
constexpr size_t OFF_QA    = OFF_QE + 1024;
}

__device__ inline float wave_sum(float v) {
#pragma unroll
  for (int off = 32; off > 0; off >>= 1) v += __shfl_xor(v, off, 64);
  return v;
}

// --- R2: split-k partials of q = x @ qW  (weights shared across batches) -----
__global__ __launch_bounds__(256) void k_qpart(
    const float* __restrict__ inp, const float* __restrict__ emo,
    const float* __restrict__ eW, const float* __restrict__ aW,
    const int* __restrict__ cl, float* __restrict__ ws)
{
  int c = blockIdx.x;          // k-chunk 0..15 (16 k's each)
  int m = blockIdx.y;          // 0=emo (x=tv+temo), 1=act (x=tv)
  int d = threadIdx.x;
  __shared__ float xs[B][16];
  if (d < 64) {
    int b = d >> 4, kk = d & 15;
    int t = cl[b] - 1;
    size_t idx = ((size_t)b*N + t)*D + c*16 + kk;
    float v = inp[idx];
    if (m == 0) v += emo[idx];
    xs[b][kk] = v;
  }
  __syncthreads();
  const float* Wq = (m ? aW : eW) + (size_t)D*D;   // lin_W[1]
  float acc0 = 0.f, acc1 = 0.f, acc2 = 0.f, acc3 = 0.f;
#pragma unroll
  for (int kk = 0; kk < 16; ++kk) {
    int k = c*16 + kk;
    float w = Wq[(size_t)k*D + d];
    acc0 += xs[0][kk]*w; acc1 += xs[1][kk]*w;
    acc2 += xs[2][kk]*w; acc3 += xs[3][kk]*w;
  }
  size_t base = OFF_PARTQ + ((size_t)(m*16 + c)*4)*256 + d;
  ws[base + 0*256] = acc0; ws[base + 1*256] = acc1;
  ws[base + 2*256] = acc2; ws[base + 3*256] = acc3;
}

// --- R2: q = sum partials + qb; qc; scalar dots -------------------------------
__global__ __launch_bounds__(256) void k_qfinish(
    const float* __restrict__ eb, const float* __restrict__ ab,
    const float* __restrict__ cskb, const float* __restrict__ a,
    float* __restrict__ ws)
{
  int b = blockIdx.x, m = blockIdx.y, d = threadIdx.x;
  __shared__ float red[D];
  const float* bias = m ? ab : eb;
  float q = bias[D + d];
#pragma unroll
  for (int c = 0; c < 16; ++c)
    q += ws[OFF_PARTQ + ((size_t)(m*16 + c)*4 + b)*256 + d];
  ws[(m ? OFF_QA : OFF_QE) + (size_t)b*D + d] = q;
  ws[(m ? QCA : QCE) + (size_t)b*D + d] = q + bias[3*D + d] + bias[0*D + d];
  red[d] = q * (bias[2*D + d] + bias[0*D + d]);
  __syncthreads();
  for (int s = 128; s > 0; s >>= 1) { if (d < s) red[d] += red[d+s]; __syncthreads(); }
  if (d == 0) ws[(m ? CAc : CEc) + b] = red[0];
  if (m == 1 && b == 0) {
    __syncthreads();
    red[d] = cskb[d] * a[D + d];
    __syncthreads();
    for (int s = 128; s > 0; s >>= 1) { if (d < s) red[d] += red[d+s]; __syncthreads(); }
    if (d == 0) ws[C2c] = 2.0f * red[0];
  }
}

// --- R2: 17 row-major matvecs, wave-per-row, coalesced ------------------------
__global__ __launch_bounds__(256) void k_rowdots(
    const float* __restrict__ eW, const float* __restrict__ aW,
    const float* __restrict__ cskW, const float* __restrict__ a,
    float* __restrict__ ws)
{
  int job = blockIdx.y;
  int wid = threadIdx.x >> 6, lane = threadIdx.x & 63;
  int row = blockIdx.x*4 + wid;
  __shared__ float vec[D];
  const float* M; size_t outo;
  if (job < 16) {
    int b = job >> 2, m = (job >> 1) & 1, which = job & 1;
    const float* base = m ? aW : eW;
    M = base + (which ? 0 : (size_t)2*D*D);          // wW : kW
    if (threadIdx.x < D)
      vec[threadIdx.x] = ws[(m ? OFF_QA : OFF_QE) + (size_t)b*D + threadIdx.x];
    outo = (which ? (m ? WQA : WQE) : (m ? KQA : KQE)) + (size_t)b*D;
  } else {
    M = cskW;
    if (threadIdx.x < D) vec[threadIdx.x] = a[D + threadIdx.x];
    outo = CA2;
  }
  __syncthreads();
  float4 w = *reinterpret_cast<const float4*>(&M[(size_t)row*D + lane*4]);
  float s = w.x*vec[lane*4] + w.y*vec[lane*4+1] + w.z*vec[lane*4+2] + w.w*vec[lane*4+3];
  s = wave_sum(s);
  if (lane == 0) ws[outo + row] = s;
}

// --- generic f32 GEMM: C(8192,256) = A1(8192,K)@B1(K,256) [+ A2@B2] ----------
__global__ __launch_bounds__(256) void k_gemm(
    const float* __restrict__ A1, const float* __restrict__ B1,
    const float* __restrict__ A2, const float* __restrict__ B2,
    float* __restrict__ C, int K)
{
  __shared__ float As[16][64];
  __shared__ float Bs[16][64];
  const int tid = threadIdx.x;
  const int tx = tid & 15, ty = tid >> 4;
  const int m0 = blockIdx.x * 64, n0 = blockIdx.y * 64;
  const int lr = tid >> 2, lk = (tid & 3) << 2;
  const int bk = tid >> 4, bc = (tid & 15) << 2;
  float acc[4][4] = {{0.f}};
  for (int src = 0; src < 2; ++src) {
    const float* A  = src ? A2 : A1;
    const float* Bm = src ? B2 : B1;
    if (!A) break;
    for (int k0 = 0; k0 < K; k0 += 16) {
      float4 av = *reinterpret_cast<const float4*>(&A[(size_t)(m0 + lr)*K + k0 + lk]);
      float4 bv = *reinterpret_cast<const float4*>(&Bm[(size_t)(k0 + bk)*D + n0 + bc]);
      __syncthreads();
      As[lk+0][lr] = av.x; As[lk+1][lr] = av.y; As[lk+2][lr] = av.z; As[lk+3][lr] = av.w;
      *reinterpret_cast<float4*>(&Bs[bk][bc]) = bv;
      __syncthreads();
#pragma unroll
      for (int k = 0; k < 16; ++k) {
        float a0 = As[k][ty*4+0], a1 = As[k][ty*4+1], a2 = As[k][ty*4+2], a3 = As[k][ty*4+3];
        float b0 = Bs[k][tx*4+0], b1 = Bs[k][tx*4+1], b2 = Bs[k][tx*4+2], b3 = Bs[k][tx*4+3];
        acc[0][0] += a0*b0; acc[0][1] += a0*b1; acc[0][2] += a0*b2; acc[0][3] += a0*b3;
        acc[1][0] += a1*b0; acc[1][1] += a1*b1; acc[1][2] += a1*b2; acc[1][3] += a1*b3;
        acc[2][0] += a2*b0; acc[2][1] += a2*b1; acc[2][2] += a2*b2; acc[2][3] += a2*b3;
        acc[3][0] += a3*b0; acc[3][1] += a3*b1; acc[3][2] += a3*b2; acc[3][3] += a3*b3;
      }
    }
  }
#pragma unroll
  for (int i = 0; i < 4; ++i)
#pragma unroll
    for (int j = 0; j < 4; ++j)
      C[(size_t)(m0 + ty*4 + i)*D + n0 + tx*4 + j] = acc[i][j];
}

// --- u = tim*icsk + (1-tim)*ocsk for both measures ---------------------------
__global__ __launch_bounds__(256) void k_u(
    const float* __restrict__ ei, const float* __restrict__ eo,
    const float* __restrict__ ai, const float* __restrict__ ao,
    const int* __restrict__ cl, const int* __restrict__ intra,
    float* __restrict__ ws)
{
  size_t g = (size_t)blockIdx.x*256 + threadIdx.x;
  size_t base = g << 2;
  int b = (int)(base >> 19);              // N*D = 2^19
  int n = (int)((base >> 8) & (N - 1));
  int t = cl[b] - 1;
  float tm = (float)intra[(size_t)b*N*N + (size_t)t*N + n];
  float om = 1.0f - tm;
  float4 vei = *(const float4*)&ei[base];
  float4 veo = *(const float4*)&eo[base];
  float4 vai = *(const float4*)&ai[base];
  float4 vao = *(const float4*)&ao[base];
  float4 ue, ua;
  ue.x = tm*vei.x + om*veo.x; ue.y = tm*vei.y + om*veo.y;
  ue.z = tm*vei.z + om*veo.z; ue.w = tm*vei.w + om*veo.w;
  ua.x = tm*vai.x + om*vao.x; ua.y = tm*vai.y + om*vao.y;
  ua.z = tm*vai.z + om*vao.z; ua.w = tm*vai.w + om*vao.w;
  *(float4*)&ws[OFF_UE + base] = ue;
  *(float4*)&ws[OFF_UA + base] = ua;
}

// --- s1 = h.a1 ; s2 = h.a2 + (bef+aft).ca2 + c2 ------------------------------
__global__ __launch_bounds__(256) void k_s12(
    const float* __restrict__ bef, const float* __restrict__ aft,
    const float* __restrict__ a, float* __restrict__ ws)
{
  int wid  = (int)(((size_t)blockIdx.x*256 + threadIdx.x) >> 6);
  int lane = threadIdx.x & 63;
  int d0 = lane << 2;
  float4 a1 = *(const float4*)&a[d0];
  float4 a2 = *(const float4*)&a[D + d0];
  float4 cv = *(const float4*)&ws[CA2 + d0];
  float c2  = ws[C2c];
  for (int rr = 0; rr < 4; ++rr) {
    int row = wid*4 + rr;
    float4 h4 = *(const float4*)&ws[OFF_H + (size_t)row*D + d0];
    float4 b4 = *(const float4*)&bef[(size_t)row*D + d0];
    float4 f4 = *(const float4*)&aft[(size_t)row*D + d0];
    float s1 = h4.x*a1.x + h4.y*a1.y + h4.z*a1.z + h4.w*a1.w;
    float s2 = h4.x*a2.x + h4.y*a2.y + h4.z*a2.z + h4.w*a2.w
             + (b4.x+f4.x)*cv.x + (b4.y+f4.y)*cv.y
             + (b4.z+f4.z)*cv.z + (b4.w+f4.w)*cv.w;
    s1 = wave_sum(s1); s2 = wave_sum(s2);
    if (lane == 0) { ws[OFF_S1 + row] = s1; ws[OFF_S2 + row] = s2 + c2; }
  }
}

// --- bitonic sort of s2 per batch + scalar prefix sums of e^{s2}, e^{a s2} ---
__global__ __launch_bounds__(1024) void k_sort(float* __restrict__ ws)
{
  int b = blockIdx.x, t = threadIdx.x;
  __shared__ float skey[N];
  __shared__ int   sidxl[N];
  skey[t]        = ws[OFF_S2 + (size_t)b*N + t];
  skey[t + 1024] = ws[OFF_S2 + (size_t)b*N + t + 1024];
  sidxl[t] = t; sidxl[t + 1024] = t + 1024;
  __syncthreads();
  for (int k = 2; k <= N; k <<= 1)
    for (int j = k >> 1; j > 0; j >>= 1) {
      for (int h = 0; h < 2; ++h) {
        int i = t + h*1024;
        int l = i ^ j;
        if (l > i) {
          float ki = skey[i], kl = skey[l];
          bool up = ((i & k) == 0);
          if (up ? (ki > kl) : (ki < kl)) {
            skey[i] = kl; skey[l] = ki;
            int tmp = sidxl[i]; sidxl[i] = sidxl[l]; sidxl[l] = tmp;
          }
        }
      }
      __syncthreads();
    }
  ws[OFF_SV + (size_t)b*N + t]        = skey[t];
  ws[OFF_SV + (size_t)b*N + t + 1024] = skey[t + 1024];
  int* wsi = (int*)ws;
  wsi[OFF_SIDX + (size_t)b*N + t]        = sidxl[t];
  wsi[OFF_SIDX + (size_t)b*N + t + 1024] = sidxl[t + 1024];
  ws[OFF_WP + (size_t)b*N + t]        = expf(skey[t]);
  ws[OFF_WP + (size_t)b*N + t + 1024] = expf(skey[t + 1024]);
  ws[OFF_WN + (size_t)b*N + t]        = expf(ALPHA*skey[t]);
  ws[OFF_WN + (size_t)b*N + t + 1024] = expf(ALPHA*skey[t + 1024]);
  __syncthreads();
  float* buf = (float*)sidxl;
  for (int pass = 0; pass < 2; ++pass) {
    float m = pass ? ALPHA : 1.0f;
    buf[t]        = expf(m*skey[t]);
    buf[t + 1024] = expf(m*skey[t + 1024]);
    __syncthreads();
    for (int off = 1; off < N; off <<= 1) {
      float v0 = (t >= off)        ? buf[t - off]        : 0.f;
      float v1 = (t + 1024 >= off) ? buf[t + 1024 - off] : 0.f;
      __syncthreads();
      buf[t] += v0; buf[t + 1024] += v1;
      __syncthreads();
    }
    size_t zo = (pass ? OFF_ZN : OFF_ZP) + (size_t)b*(N+1);
    if (t == 0) ws[zo] = 0.f;
    ws[zo + t + 1]    = buf[t];
    ws[zo + t + 1025] = buf[t + 1024];
    __syncthreads();
  }
}

// --- vector prefix sums over sorted order: 3-pass ----------------------------
__global__ __launch_bounds__(256) void k_p1(float* __restrict__ ws)
{
  int c = blockIdx.x, b = blockIdx.y, d = threadIdx.x;
  const int*   sidx = (const int*)ws + OFF_SIDX + (size_t)b*N;
  const float* wp = ws + OFF_WP + (size_t)b*N;
  const float* wn = ws + OFF_WN + (size_t)b*N;
  const float* h  = ws + OFF_H + (size_t)b*N*D;
  float ap = 0.f, an = 0.f;
  for (int r = c*64; r < c*64 + 64; ++r) {
    float hv = h[(size_t)sidx[r]*D + d];
    ap += wp[r]*hv; an += wn[r]*hv;
  }
  ws[OFF_PARTP + ((size_t)b*32 + c)*D + d] = ap;
  ws[OFF_PARTN + ((size_t)b*32 + c)*D + d] = an;
}

__global__ __launch_bounds__(256) void k_p2(float* __restrict__ ws)
{
  int b = blockIdx.x, d = threadIdx.x;
  float ap = 0.f, an = 0.f;
  for (int c = 0; c < 32; ++c) {
    size_t o = ((size_t)b*32 + c)*D + d;
    float tp = ws[OFF_PARTP + o], tn = ws[OFF_PARTN + o];
    ws[OFF_OFFP + o] = ap; ws[OFF_OFFN + o] = an;
    ap += tp; an += tn;
  }
}

__global__ __launch_bounds__(256) void k_p3(float* __restrict__ ws)
{
  int c = blockIdx.x, b = blockIdx.y, d = threadIdx.x;
  const int*   sidx = (const int*)ws + OFF_SIDX + (size_t)b*N;
  const float* wp = ws + OFF_WP + (size_t)b*N;
  const float* wn = ws + OFF_WN + (size_t)b*N;
  const float* h  = ws + OFF_H + (size_t)b*N*D;
  float ap = ws[OFF_OFFP + ((size_t)b*32 + c)*D + d];
  float an = ws[OFF_OFFN + ((size_t)b*32 + c)*D + d];
  for (int r = c*64; r < c*64 + 64; ++r) {
    ws[OFF_PPOS + ((size_t)b*(N+1) + r)*D + d] = ap;
    ws[OFF_PNEG + ((size_t)b*(N+1) + r)*D + d] = an;
    float hv = h[(size_t)sidx[r]*D + d];
    ap += wp[r]*hv; an += wn[r]*hv;
  }
  if (c == 31) {
    ws[OFF_PPOS + ((size_t)b*(N+1) + N)*D + d] = ap;
    ws[OFF_PNEG + ((size_t)b*(N+1) + N)*D + d] = an;
  }
}

// --- R1: per-row rank + folded softmax coefficients --------------------------
__global__ __launch_bounds__(256) void k_rank(float* __restrict__ ws)
{
  int b = blockIdx.y;
  int i = blockIdx.x * 256 + threadIdx.x;
  __shared__ float sv[N];
  for (int r = threadIdx.x; r < N; r += 256) sv[r] = ws[OFF_SV + (size_t)b*N + r];
  __syncthreads();
  float s1i = ws[OFF_S1 + (size_t)b*N + i];
  float th = -s1i;
  int lo = 0, hi = N;
  while (lo < hi) { int mid = (lo + hi) >> 1; if (sv[mid] <= th) lo = mid + 1; else hi = mid; }
  int r = lo;
  float ep = expf(s1i), en = expf(ALPHA*s1i);
  float zp  = ws[OFF_ZP + (size_t)b*(N+1) + r];
  float zn  = ws[OFF_ZN + (size_t)b*(N+1) + r];
  float zpT = ws[OFF_ZP + (size_t)b*(N+1) + N];
  float den = ep*(zpT - zp) + en*zn;
  ((int*)ws)[OFF_RNK + (size_t)b*N + i] = r;
  ws[OFF_C0 + (size_t)b*N + i] = ep/den;
  ws[OFF_C1 + (size_t)b*N + i] = en/den;
}

// --- R1: h_prime gather: hp[i,d] = c0*(totp[d]-pp[r,d]) + c1*pn[r,d] ---------
__global__ __launch_bounds__(256) void k_hprime2(float* __restrict__ ws)
{
  int b = blockIdx.y, d = threadIdx.x;
  int i0 = blockIdx.x * 8;
  float totp = ws[OFF_PPOS + ((size_t)b*(N+1) + N)*D + d];
#pragma unroll
  for (int ii = 0; ii < 8; ++ii) {
    int i = i0 + ii;
    int   r  = ((const int*)ws)[OFF_RNK + (size_t)b*N + i];
    float c0 = ws[OFF_C0 + (size_t)b*N + i];
    float c1 = ws[OFF_C1 + (size_t)b*N + i];
    float pp = ws[OFF_PPOS + ((size_t)b*(N+1) + r)*D + d];
    float pn = ws[OFF_PNEG + ((size_t)b*(N+1) + r)*D + d];
    ws[OFF_HP + ((size_t)b*N + i)*D + d] = c0*(totp - pp) + c1*pn;
  }
}

// --- logits: inv*(h'.kq + u.wq + c) ------------------------------------------
__global__ __launch_bounds__(256) void k_logits(float* __restrict__ ws)
{
  int wid  = (int)(((size_t)blockIdx.x*256 + threadIdx.x) >> 6);
  int lane = threadIdx.x & 63;
  int d0 = lane << 2;
  int row0 = wid*4;
  int b = row0 >> 11;
  float4 kqe = *(const float4*)&ws[KQE + (size_t)b*D + d0];
  float4 wqe = *(const float4*)&ws[WQE + (size_t)b*D + d0];
  float4 kqa = *(const float4*)&ws[KQA + (size_t)b*D + d0];
  float4 wqa = *(const float4*)&ws[WQA + (size_t)b*D + d0];
  float ce = ws[CEc + b], ca = ws[CAc + b];
  for (int rr = 0; rr < 4; ++rr) {
    int row = row0 + rr;
    float4 hp = *(const float4*)&ws[OFF_HP + (size_t)row*D + d0];
    float4 ue = *(const float4*)&ws[OFF_UE + (size_t)row*D + d0];
    float4 ua = *(const float4*)&ws[OFF_UA + (size_t)row*D + d0];
    float se = hp.x*kqe.x + hp.y*kqe.y + hp.z*kqe.z + hp.w*kqe.w
             + ue.x*wqe.x + ue.y*wqe.y + ue.z*wqe.z + ue.w*wqe.w;
    float sa = hp.x*kqa.x + hp.y*kqa.y + hp.z*kqa.z + hp.w*kqa.w
             + ua.x*wqa.x + ua.y*wqa.y + ua.z*wqa.z + ua.w*wqa.w;
    se = wave_sum(se); sa = wave_sum(sa);
    if (lane == 0) {
      ws[OFF_LE + row] = (se + ce) * INVS;
      ws[OFF_LA + row] = (sa + ca) * INVS;
    }
  }
}

// --- probs softmax over N, writes directly to d_out --------------------------
__global__ __launch_bounds__(1024) void k_softmax(const float* __restrict__ ws,
                                                  float* __restrict__ out)
{
  int b = blockIdx.x, t = threadIdx.x;
  __shared__ float red[1024];
  for (int m = 0; m < 2; ++m) {
    const float* l = ws + (m ? OFF_LA : OFF_LE) + (size_t)b*N;
    float* p = out + (size_t)B*N*D + (size_t)m*B*N + (size_t)b*N;
    float v0 = l[t], v1 = l[t + 1024];
    red[t] = fmaxf(v0, v1);
    __syncthreads();
    for (int s = 512; s > 0; s >>= 1) { if (t < s) red[t] = fmaxf(red[t], red[t+s]); __syncthreads(); }
    float mx = red[0];
    __syncthreads();
    float e0 = expf(v0 - mx), e1 = expf(v1 - mx);
    red[t] = e0 + e1;
    __syncthreads();
    for (int s = 512; s > 0; s >>= 1) { if (t < s) red[t] += red[t+s]; __syncthreads(); }
    float inv = 1.0f / red[0];
    __syncthreads();
    p[t] = e0 * inv; p[t + 1024] = e1 * inv;
    __syncthreads();
  }
}

// --- final: out = relu(h' + inp + pe*(qce+Ve) + pa*(qca+Va)) ------------------
__global__ __launch_bounds__(256) void k_final(
    const float* __restrict__ inp, const float* __restrict__ ws,
    float* __restrict__ out)
{
  size_t g = (size_t)blockIdx.x*256 + threadIdx.x;
  size_t base = g << 2;
  int b  = (int)(base >> 19);
  int n  = (int)((base >> 8) & (N - 1));
  int d0 = (int)(base & (D - 1));
  float pe = out[(size_t)B*N*D + (size_t)b*N + n];
  float pa = out[(size_t)B*N*D + (size_t)B*N + (size_t)b*N + n];
  float4 hp = *(const float4*)&ws[OFF_HP + base];
  float4 iv = *(const float4*)&inp[base];
  float4 ve = *(const float4*)&ws[OFF_VE + base];
  float4 va = *(const float4*)&ws[OFF_VA + base];
  float4 qe = *(const float4*)&ws[QCE + (size_t)b*D + d0];
  float4 qa = *(const float4*)&ws[QCA + (size_t)b*D + d0];
  float4 o;
  o.x = hp.x + iv.x + pe*(qe.x + ve.x) + pa*(qa.x + va.x);
  o.y = hp.y + iv.y + pe*(qe.y + ve.y) + pa*(qa.y + va.y);
  o.z = hp.z + iv.z + pe*(qe.z + ve.z) + pa*(qa.z + va.z);
  o.w = hp.w + iv.w + pe*(qe.w + ve.w) + pa*(qa.w + va.w);
  o.x = fmaxf(o.x, 0.f); o.y = fmaxf(o.y, 0.f);
  o.z = fmaxf(o.z, 0.f); o.w = fmaxf(o.w, 0.f);
  *(float4*)&out[base] = o;
}

extern "C" void kernel_launch(void* const* d_in, const int* in_sizes, int n_in,
                              void* d_out, int out_size, void* d_ws, size_t ws_size,
                              hipStream_t stream) {
  const float* inp  = (const float*)d_in[0];
  const float* emo  = (const float*)d_in[1];
  const float* bef  = (const float*)d_in[2];
  const float* aft  = (const float*)d_in[3];
  const float* ei   = (const float*)d_in[4];
  const float* eo   = (const float*)d_in[5];
  const float* ii   = (const float*)d_in[6];
  const float* io   = (const float*)d_in[7];
  const float* W    = (const float*)d_in[8];
  const float* a    = (const float*)d_in[9];
  const float* cskW = (const float*)d_in[10];
  const float* cskb = (const float*)d_in[11];
  const float* eW   = (const float*)d_in[12];
  const float* eb   = (const float*)d_in[13];
  const float* aW   = (const float*)d_in[14];
  const float* ab   = (const float*)d_in[15];
  const int*   cl   = (const int*)d_in[16];
  const int*   intra= (const int*)d_in[17];
  float* ws  = (float*)d_ws;
  float* out = (float*)d_out;

  k_qpart<<<dim3(16, 2), 256, 0, stream>>>(inp, emo, eW, aW, cl, ws);
  k_gemm<<<dim3(128, 4), 256, 0, stream>>>(inp, W, nullptr, nullptr, ws + OFF_H, 256);
  k_qfinish<<<dim3(B, 2), 256, 0, stream>>>(eb, ab, cskb, a, ws);
  k_u<<<2048, 256, 0, stream>>>(ei, eo, ii, io, cl, intra, ws);
  k_rowdots<<<dim3(64, 17), 256, 0, stream>>>(eW, aW, cskW, a, ws);
  k_s12<<<512, 256, 0, stream>>>(bef, aft, a, ws);
  k_sort<<<B, 1024, 0, stream>>>(ws);
  k_rank<<<dim3(8, B), 256, 0, stream>>>(ws);
  k_p1<<<dim3(32, B), 256, 0, stream>>>(ws);
  k_p2<<<B, 256, 0, stream>>>(ws);
  k_p3<<<dim3(32, B), 256, 0, stream>>>(ws);
  k_hprime2<<<dim3(256, B), 256, 0, stream>>>(ws);
  k_gemm<<<dim3(128, 4), 256, 0, stream>>>(ws + OFF_HP, eW + 3*65536, ws + OFF_UE, eW,
                                           ws + OFF_VE, 256);
  k_gemm<<<dim3(128, 4), 256, 0, stream>>>(ws + OFF_HP, aW + 3*65536, ws + OFF_UA, aW,
                                           ws + OFF_VA, 256);
  k_logits<<<512, 256, 0, stream>>>(ws);
  k_softmax<<<B, 1024, 0, stream>>>(ws, out);
  k_final<<<2048, 256, 0, stream>>>(inp, ws, out);
}

// Round 4
// 163.523 us; speedup vs baseline: 1.8636x; 1.2208x over previous
//
#include <hip/hip_runtime.h>
#include <math.h>

// ---------------------------------------------------------------------------
// Problem: B=4, N=2048, D=256.
// Key exact simplifications:
//  * intra+inter == 1  -> attention = softmax_j(leaky_relu(s1_i + s2_j)), no masks
//  * rank-1 + monotone -> h_prime via sorted-s2 prefix sums (O(N D), exact)
//  * evt / k_base / w_i / w_o folded into matvecs; only 3 big GEMMs remain
// R1: k_hprime split into k_rank + k_hprime2 (was 73us latency-bound).
// R2: k_setup split into k_qpart + k_qfinish + k_rowdots (was 64us, 4 blocks).
// R3: f32 VALU GEMMs (3x40us, MfmaUtil=0) -> bf16 MFMA (16x16x32).
//     A/B frags use the SAME (kg,reg)->k map, so any bijective k layout is
//     exact; C/D layout is the HW-verified col=lane&15, row=kg*4+reg.
// ---------------------------------------------------------------------------

namespace {
constexpr int B = 4, N = 2048, D = 256;
constexpr float ALPHA = 0.2f;
constexpr float INVS  = 0.0625f;   // 1/sqrt(256)

// ws offsets (float elements)
constexpr size_t OFF_H     = 0;                       // (B,N,D)
constexpr size_t OFF_HP    = 2097152;                 // h_prime
constexpr size_t OFF_UE    = 4194304;                 // u_emo
constexpr size_t OFF_UA    = 6291456;                 // u_act
constexpr size_t OFF_PPOS  = 8388608;                 // (B,N+1,D) prefix, later Ve
constexpr size_t OFF_PNEG  = 10486784;                // (B,N+1,D) prefix, later Va
constexpr size_t OFF_VE    = OFF_PPOS;
constexpr size_t OFF_VA    = OFF_PNEG;
constexpr size_t OFF_S1    = 12584960;                // (B,N)
constexpr size_t OFF_S2    = OFF_S1 + 8192;
constexpr size_t OFF_SV    = OFF_S2 + 8192;           // sorted s2
constexpr size_t OFF_SIDX  = OFF_SV + 8192;           // permutation (int)
constexpr size_t OFF_WP    = OFF_SIDX + 8192;         // e^{s2} sorted
constexpr size_t OFF_WN    = OFF_WP + 8192;           // e^{a s2} sorted
constexpr size_t OFF_ZP    = OFF_WN + 8192;           // (B,N+1) scalar prefix
constexpr size_t OFF_ZN    = OFF_ZP + 8196;
constexpr size_t OFF_PARTP = OFF_ZN + 8196;           // (B,32,D) chunk partials
constexpr size_t OFF_PARTN = OFF_PARTP + 32768;
constexpr size_t OFF_OFFP  = OFF_PARTN + 32768;
constexpr size_t OFF_OFFN  = OFF_OFFP + 32768;
constexpr size_t OFF_LE    = OFF_OFFN + 32768;        // emo logits
constexpr size_t OFF_LA    = OFF_LE + 8192;           // act logits
constexpr size_t OFF_SET   = OFF_LA + 8192;
constexpr size_t KQE = OFF_SET + 0;      // kW@q per batch (B,256)
constexpr size_t WQE = OFF_SET + 1024;
constexpr size_t KQA = OFF_SET + 2048;
constexpr size_t WQA = OFF_SET + 3072;
constexpr size_t QCE = OFF_SET + 4096;   // q + vb + wb
constexpr size_t QCA = OFF_SET + 5120;
constexpr size_t CA2 = OFF_SET + 6144;   // csk_W @ a2 (256)
constexpr size_t CEc = OFF_SET + 6400;   // q.(kb+wb) per batch
constexpr size_t CAc = OFF_SET + 6404;
constexpr size_t C2c = OFF_SET + 6408;   // 2*csk_b.a2
constexpr size_t OFF_RNK   = OFF_SET + 8192;          // (B,N) int
constexpr size_t OFF_C0    = OFF_RNK + 8192;          // ep/den
constexpr size_t OFF_C1    = OFF_C0 + 8192;           // en/den
constexpr size_t OFF_PARTQ = OFF_C1 + 8192;           // [m2][c16][b4][256]
constexpr size_t OFF_QE    = OFF_PARTQ + 32768;       // (B,256)
constexpr size_t OFF_QA    = OFF_QE + 1024;
// R3: bf16 buffers (ushort views; sizes in float elems)
constexpr size_t OFF_IB    = 12865544;                // inp bf16 (2M ushort)
constexpr size_t OFF_HPB   = OFF_IB  + 1048576;
constexpr size_t OFF_UEB   = OFF_HPB + 1048576;
constexpr size_t OFF_UAB   = OFF_UEB + 1048576;
constexpr size_t OFF_BT    = OFF_UAB + 1048576;       // 5 x 256x256 bf16 B^T
}

typedef __attribute__((ext_vector_type(8))) short bf16x8;
typedef __attribute__((ext_vector_type(4))) float f32x4;

__device__ inline float wave_sum(float v) {
#pragma unroll
  for (int off = 32; off > 0; off >>= 1) v += __shfl_xor(v, off, 64);
  return v;
}

__device__ inline ushort f2bf(float x) {
  union { float f; uint u; } v; v.f = x;
  return (ushort)((v.u + 0x7FFFu + ((v.u >> 16) & 1u)) >> 16);
}
__device__ inline uint pk2bf(float a, float b) {
  return (uint)f2bf(a) | ((uint)f2bf(b) << 16);
}

// --- R3: f32 -> bf16 bulk convert (inp) ---------------------------------------
__global__ __launch_bounds__(256) void k_cvt(const float* __restrict__ in,
                                             ushort* __restrict__ ob)
{
  size_t i = ((size_t)blockIdx.x*256 + threadIdx.x) * 8;
  float4 f0 = *(const float4*)&in[i], f1 = *(const float4*)&in[i+4];
  uint4 o;
  o.x = pk2bf(f0.x, f0.y); o.y = pk2bf(f0.z, f0.w);
  o.z = pk2bf(f1.x, f1.y); o.w = pk2bf(f1.z, f1.w);
  *(uint4*)&ob[i] = o;
}

// --- R3: transpose + convert the 5 weight matrices (256x256) ------------------
__global__ __launch_bounds__(256) void k_bt(
    const float* __restrict__ Wm, const float* __restrict__ eW,
    const float* __restrict__ aW, ushort* __restrict__ bt)
{
  int m = blockIdx.y;
  const float* src = (m == 0) ? Wm : (m == 1) ? eW + 3*65536 : (m == 2) ? eW
                   : (m == 3) ? aW + 3*65536 : aW;
  ushort* dst = bt + (size_t)m*65536;
  int k0 = (blockIdx.x >> 2)*64, n0 = (blockIdx.x & 3)*64;
  __shared__ float tile[64][65];
  int r = threadIdx.x >> 2, c0 = (threadIdx.x & 3)*16;
#pragma unroll
  for (int cc = 0; cc < 16; cc += 4)
    *(float4*)&tile[r][c0+cc] = *(const float4*)&src[(size_t)(k0+r)*256 + n0 + c0 + cc];
  __syncthreads();
  int n = threadIdx.x >> 2, kq = (threadIdx.x & 3)*16;
  uint4 o0, o1;
  o0.x = pk2bf(tile[kq+ 0][n], tile[kq+ 1][n]);
  o0.y = pk2bf(tile[kq+ 2][n], tile[kq+ 3][n]);
  o0.z = pk2bf(tile[kq+ 4][n], tile[kq+ 5][n]);
  o0.w = pk2bf(tile[kq+ 6][n], tile[kq+ 7][n]);
  o1.x = pk2bf(tile[kq+ 8][n], tile[kq+ 9][n]);
  o1.y = pk2bf(tile[kq+10][n], tile[kq+11][n]);
  o1.z = pk2bf(tile[kq+12][n], tile[kq+13][n]);
  o1.w = pk2bf(tile[kq+14][n], tile[kq+15][n]);
  *(uint4*)&dst[(size_t)(n0+n)*256 + k0 + kq]     = o0;
  *(uint4*)&dst[(size_t)(n0+n)*256 + k0 + kq + 8] = o1;
}

// --- R3: MFMA bf16 GEMM: C(8192,256 f32) = A1@B1 [+ A2@B2] --------------------
// A: bf16 row-major (8192,256). B: bf16 PRE-TRANSPOSED (N=256 rows, K cols).
// BM=64, BN=128, BK=32; 4 waves (2M x 2N), wave = 32x64 = 2x4 16x16 frags.
__global__ __launch_bounds__(256) void k_mgemm(
    const ushort* __restrict__ A1, const ushort* __restrict__ B1,
    const ushort* __restrict__ A2, const ushort* __restrict__ B2,
    float* __restrict__ C)
{
  __shared__ ushort As[64*40];                       // rows padded to 40 elems
  const int t = threadIdx.x;
  const int lane = t & 63, w = t >> 6;
  const int wm = w >> 1, wn = w & 1;
  const int laneN = lane & 15, kg = lane >> 4;
  const int m0 = blockIdx.x * 64, n0 = blockIdx.y * 128;
  const int srow = t >> 2, sq = t & 3;               // staging row / 8-elem quad
  f32x4 acc[2][4] = {};
  for (int src = 0; src < 2; ++src) {
    const ushort* A  = src ? A2 : A1;
    const ushort* Bt = src ? B2 : B1;
    if (!A) break;
    for (int k0 = 0; k0 < 256; k0 += 32) {
      __syncthreads();
      uint4 av = *(const uint4*)&A[(size_t)(m0 + srow)*256 + k0 + sq*8];
      *(uint4*)&As[srow*40 + sq*8] = av;
      __syncthreads();
      bf16x8 bf[4];
#pragma unroll
      for (int j = 0; j < 4; ++j)
        bf[j] = *(const bf16x8*)&Bt[(size_t)(n0 + wn*64 + j*16 + laneN)*256 + k0 + kg*8];
#pragma unroll
      for (int i = 0; i < 2; ++i) {
        bf16x8 af = *(const bf16x8*)&As[(wm*32 + i*16 + laneN)*40 + kg*8];
#pragma unroll
        for (int j = 0; j < 4; ++j)
          acc[i][j] = __builtin_amdgcn_mfma_f32_16x16x32_bf16(af, bf[j], acc[i][j], 0, 0, 0);
      }
    }
  }
#pragma unroll
  for (int i = 0; i < 2; ++i)
#pragma unroll
    for (int j = 0; j < 4; ++j)
#pragma unroll
      for (int r = 0; r < 4; ++r)
        C[(size_t)(m0 + wm*32 + i*16 + kg*4 + r)*256 + n0 + wn*64 + j*16 + laneN]
            = acc[i][j][r];
}

// --- R2: split-k partials of q = x @ qW ---------------------------------------
__global__ __launch_bounds__(256) void k_qpart(
    const float* __restrict__ inp, const float* __restrict__ emo,
    const float* __restrict__ eW, const float* __restrict__ aW,
    const int* __restrict__ cl, float* __restrict__ ws)
{
  int c = blockIdx.x;          // k-chunk 0..15
  int m = blockIdx.y;          // 0=emo, 1=act
  int d = threadIdx.x;
  __shared__ float xs[B][16];
  if (d < 64) {
    int b = d >> 4, kk = d & 15;
    int t = cl[b] - 1;
    size_t idx = ((size_t)b*N + t)*D + c*16 + kk;
    float v = inp[idx];
    if (m == 0) v += emo[idx];
    xs[b][kk] = v;
  }
  __syncthreads();
  const float* Wq = (m ? aW : eW) + (size_t)D*D;   // lin_W[1]
  float acc0 = 0.f, acc1 = 0.f, acc2 = 0.f, acc3 = 0.f;
#pragma unroll
  for (int kk = 0; kk < 16; ++kk) {
    int k = c*16 + kk;
    float w = Wq[(size_t)k*D + d];
    acc0 += xs[0][kk]*w; acc1 += xs[1][kk]*w;
    acc2 += xs[2][kk]*w; acc3 += xs[3][kk]*w;
  }
  size_t base = OFF_PARTQ + ((size_t)(m*16 + c)*4)*256 + d;
  ws[base + 0*256] = acc0; ws[base + 1*256] = acc1;
  ws[base + 2*256] = acc2; ws[base + 3*256] = acc3;
}

// --- R2: q = sum partials + qb; qc; scalar dots --------------------------------
__global__ __launch_bounds__(256) void k_qfinish(
    const float* __restrict__ eb, const float* __restrict__ ab,
    const float* __restrict__ cskb, const float* __restrict__ a,
    float* __restrict__ ws)
{
  int b = blockIdx.x, m = blockIdx.y, d = threadIdx.x;
  __shared__ float red[D];
  const float* bias = m ? ab : eb;
  float q = bias[D + d];
#pragma unroll
  for (int c = 0; c < 16; ++c)
    q += ws[OFF_PARTQ + ((size_t)(m*16 + c)*4 + b)*256 + d];
  ws[(m ? OFF_QA : OFF_QE) + (size_t)b*D + d] = q;
  ws[(m ? QCA : QCE) + (size_t)b*D + d] = q + bias[3*D + d] + bias[0*D + d];
  red[d] = q * (bias[2*D + d] + bias[0*D + d]);
  __syncthreads();
  for (int s = 128; s > 0; s >>= 1) { if (d < s) red[d] += red[d+s]; __syncthreads(); }
  if (d == 0) ws[(m ? CAc : CEc) + b] = red[0];
  if (m == 1 && b == 0) {
    __syncthreads();
    red[d] = cskb[d] * a[D + d];
    __syncthreads();
    for (int s = 128; s > 0; s >>= 1) { if (d < s) red[d] += red[d+s]; __syncthreads(); }
    if (d == 0) ws[C2c] = 2.0f * red[0];
  }
}

// --- R2: 17 row-major matvecs, wave-per-row, coalesced -------------------------
__global__ __launch_bounds__(256) void k_rowdots(
    const float* __restrict__ eW, const float* __restrict__ aW,
    const float* __restrict__ cskW, const float* __restrict__ a,
    float* __restrict__ ws)
{
  int job = blockIdx.y;
  int wid = threadIdx.x >> 6, lane = threadIdx.x & 63;
  int row = blockIdx.x*4 + wid;
  __shared__ float vec[D];
  const float* M; size_t outo;
  if (job < 16) {
    int b = job >> 2, m = (job >> 1) & 1, which = job & 1;
    const float* base = m ? aW : eW;
    M = base + (which ? 0 : (size_t)2*D*D);          // wW : kW
    if (threadIdx.x < D)
      vec[threadIdx.x] = ws[(m ? OFF_QA : OFF_QE) + (size_t)b*D + threadIdx.x];
    outo = (which ? (m ? WQA : WQE) : (m ? KQA : KQE)) + (size_t)b*D;
  } else {
    M = cskW;
    if (threadIdx.x < D) vec[threadIdx.x] = a[D + threadIdx.x];
    outo = CA2;
  }
  __syncthreads();
  float4 w = *reinterpret_cast<const float4*>(&M[(size_t)row*D + lane*4]);
  float s = w.x*vec[lane*4] + w.y*vec[lane*4+1] + w.z*vec[lane*4+2] + w.w*vec[lane*4+3];
  s = wave_sum(s);
  if (lane == 0) ws[outo + row] = s;
}

// --- u = tim*icsk + (1-tim)*ocsk for both measures (+bf16 copies) -------------
__global__ __launch_bounds__(256) void k_u(
    const float* __restrict__ ei, const float* __restrict__ eo,
    const float* __restrict__ ai, const float* __restrict__ ao,
    const int* __restrict__ cl, const int* __restrict__ intra,
    float* __restrict__ ws, ushort* __restrict__ ueb, ushort* __restrict__ uab)
{
  size_t g = (size_t)blockIdx.x*256 + threadIdx.x;
  size_t base = g << 2;
  int b = (int)(base >> 19);              // N*D = 2^19
  int n = (int)((base >> 8) & (N - 1));
  int t = cl[b] - 1;
  float tm = (float)intra[(size_t)b*N*N + (size_t)t*N + n];
  float om = 1.0f - tm;
  float4 vei = *(const float4*)&ei[base];
  float4 veo = *(const float4*)&eo[base];
  float4 vai = *(const float4*)&ai[base];
  float4 vao = *(const float4*)&ao[base];
  float4 ue, ua;
  ue.x = tm*vei.x + om*veo.x; ue.y = tm*vei.y + om*veo.y;
  ue.z = tm*vei.z + om*veo.z; ue.w = tm*vei.w + om*veo.w;
  ua.x = tm*vai.x + om*vao.x; ua.y = tm*vai.y + om*vao.y;
  ua.z = tm*vai.z + om*vao.z; ua.w = tm*vai.w + om*vao.w;
  *(float4*)&ws[OFF_UE + base] = ue;
  *(float4*)&ws[OFF_UA + base] = ua;
  uint2 pe = { pk2bf(ue.x, ue.y), pk2bf(ue.z, ue.w) };
  uint2 pa = { pk2bf(ua.x, ua.y), pk2bf(ua.z, ua.w) };
  *(uint2*)&ueb[base] = pe;
  *(uint2*)&uab[base] = pa;
}

// --- s1 = h.a1 ; s2 = h.a2 + (bef+aft).ca2 + c2 -------------------------------
__global__ __launch_bounds__(256) void k_s12(
    const float* __restrict__ bef, const float* __restrict__ aft,
    const float* __restrict__ a, float* __restrict__ ws)
{
  int wid  = (int)(((size_t)blockIdx.x*256 + threadIdx.x) >> 6);
  int lane = threadIdx.x & 63;
  int d0 = lane << 2;
  float4 a1 = *(const float4*)&a[d0];
  float4 a2 = *(const float4*)&a[D + d0];
  float4 cv = *(const float4*)&ws[CA2 + d0];
  float c2  = ws[C2c];
  for (int rr = 0; rr < 4; ++rr) {
    int row = wid*4 + rr;
    float4 h4 = *(const float4*)&ws[OFF_H + (size_t)row*D + d0];
    float4 b4 = *(const float4*)&bef[(size_t)row*D + d0];
    float4 f4 = *(const float4*)&aft[(size_t)row*D + d0];
    float s1 = h4.x*a1.x + h4.y*a1.y + h4.z*a1.z + h4.w*a1.w;
    float s2 = h4.x*a2.x + h4.y*a2.y + h4.z*a2.z + h4.w*a2.w
             + (b4.x+f4.x)*cv.x + (b4.y+f4.y)*cv.y
             + (b4.z+f4.z)*cv.z + (b4.w+f4.w)*cv.w;
    s1 = wave_sum(s1); s2 = wave_sum(s2);
    if (lane == 0) { ws[OFF_S1 + row] = s1; ws[OFF_S2 + row] = s2 + c2; }
  }
}

// --- bitonic sort of s2 per batch + scalar prefix sums ------------------------
__global__ __launch_bounds__(1024) void k_sort(float* __restrict__ ws)
{
  int b = blockIdx.x, t = threadIdx.x;
  __shared__ float skey[N];
  __shared__ int   sidxl[N];
  skey[t]        = ws[OFF_S2 + (size_t)b*N + t];
  skey[t + 1024] = ws[OFF_S2 + (size_t)b*N + t + 1024];
  sidxl[t] = t; sidxl[t + 1024] = t + 1024;
  __syncthreads();
  for (int k = 2; k <= N; k <<= 1)
    for (int j = k >> 1; j > 0; j >>= 1) {
      for (int h = 0; h < 2; ++h) {
        int i = t + h*1024;
        int l = i ^ j;
        if (l > i) {
          float ki = skey[i], kl = skey[l];
          bool up = ((i & k) == 0);
          if (up ? (ki > kl) : (ki < kl)) {
            skey[i] = kl; skey[l] = ki;
            int tmp = sidxl[i]; sidxl[i] = sidxl[l]; sidxl[l] = tmp;
          }
        }
      }
      __syncthreads();
    }
  ws[OFF_SV + (size_t)b*N + t]        = skey[t];
  ws[OFF_SV + (size_t)b*N + t + 1024] = skey[t + 1024];
  int* wsi = (int*)ws;
  wsi[OFF_SIDX + (size_t)b*N + t]        = sidxl[t];
  wsi[OFF_SIDX + (size_t)b*N + t + 1024] = sidxl[t + 1024];
  ws[OFF_WP + (size_t)b*N + t]        = expf(skey[t]);
  ws[OFF_WP + (size_t)b*N + t + 1024] = expf(skey[t + 1024]);
  ws[OFF_WN + (size_t)b*N + t]        = expf(ALPHA*skey[t]);
  ws[OFF_WN + (size_t)b*N + t + 1024] = expf(ALPHA*skey[t + 1024]);
  __syncthreads();
  float* buf = (float*)sidxl;
  for (int pass = 0; pass < 2; ++pass) {
    float m = pass ? ALPHA : 1.0f;
    buf[t]        = expf(m*skey[t]);
    buf[t + 1024] = expf(m*skey[t + 1024]);
    __syncthreads();
    for (int off = 1; off < N; off <<= 1) {
      float v0 = (t >= off)        ? buf[t - off]        : 0.f;
      float v1 = (t + 1024 >= off) ? buf[t + 1024 - off] : 0.f;
      __syncthreads();
      buf[t] += v0; buf[t + 1024] += v1;
      __syncthreads();
    }
    size_t zo = (pass ? OFF_ZN : OFF_ZP) + (size_t)b*(N+1);
    if (t == 0) ws[zo] = 0.f;
    ws[zo + t + 1]    = buf[t];
    ws[zo + t + 1025] = buf[t + 1024];
    __syncthreads();
  }
}

// --- vector prefix sums over sorted order: 3-pass ------------------------------
__global__ __launch_bounds__(256) void k_p1(float* __restrict__ ws)
{
  int c = blockIdx.x, b = blockIdx.y, d = threadIdx.x;
  const int*   sidx = (const int*)ws + OFF_SIDX + (size_t)b*N;
  const float* wp = ws + OFF_WP + (size_t)b*N;
  const float* wn = ws + OFF_WN + (size_t)b*N;
  const float* h  = ws + OFF_H + (size_t)b*N*D;
  float ap = 0.f, an = 0.f;
  for (int r = c*64; r < c*64 + 64; ++r) {
    float hv = h[(size_t)sidx[r]*D + d];
    ap += wp[r]*hv; an += wn[r]*hv;
  }
  ws[OFF_PARTP + ((size_t)b*32 + c)*D + d] = ap;
  ws[OFF_PARTN + ((size_t)b*32 + c)*D + d] = an;
}

__global__ __launch_bounds__(256) void k_p2(float* __restrict__ ws)
{
  int b = blockIdx.x, d = threadIdx.x;
  float ap = 0.f, an = 0.f;
  for (int c = 0; c < 32; ++c) {
    size_t o = ((size_t)b*32 + c)*D + d;
    float tp = ws[OFF_PARTP + o], tn = ws[OFF_PARTN + o];
    ws[OFF_OFFP + o] = ap; ws[OFF_OFFN + o] = an;
    ap += tp; an += tn;
  }
}

__global__ __launch_bounds__(256) void k_p3(float* __restrict__ ws)
{
  int c = blockIdx.x, b = blockIdx.y, d = threadIdx.x;
  const int*   sidx = (const int*)ws + OFF_SIDX + (size_t)b*N;
  const float* wp = ws + OFF_WP + (size_t)b*N;
  const float* wn = ws + OFF_WN + (size_t)b*N;
  const float* h  = ws + OFF_H + (size_t)b*N*D;
  float ap = ws[OFF_OFFP + ((size_t)b*32 + c)*D + d];
  float an = ws[OFF_OFFN + ((size_t)b*32 + c)*D + d];
  for (int r = c*64; r < c*64 + 64; ++r) {
    ws[OFF_PPOS + ((size_t)b*(N+1) + r)*D + d] = ap;
    ws[OFF_PNEG + ((size_t)b*(N+1) + r)*D + d] = an;
    float hv = h[(size_t)sidx[r]*D + d];
    ap += wp[r]*hv; an += wn[r]*hv;
  }
  if (c == 31) {
    ws[OFF_PPOS + ((size_t)b*(N+1) + N)*D + d] = ap;
    ws[OFF_PNEG + ((size_t)b*(N+1) + N)*D + d] = an;
  }
}

// --- R1: per-row rank + folded softmax coefficients ----------------------------
__global__ __launch_bounds__(256) void k_rank(float* __restrict__ ws)
{
  int b = blockIdx.y;
  int i = blockIdx.x * 256 + threadIdx.x;
  __shared__ float sv[N];
  for (int r = threadIdx.x; r < N; r += 256) sv[r] = ws[OFF_SV + (size_t)b*N + r];
  __syncthreads();
  float s1i = ws[OFF_S1 + (size_t)b*N + i];
  float th = -s1i;
  int lo = 0, hi = N;
  while (lo < hi) { int mid = (lo + hi) >> 1; if (sv[mid] <= th) lo = mid + 1; else hi = mid; }
  int r = lo;
  float ep = expf(s1i), en = expf(ALPHA*s1i);
  float zp  = ws[OFF_ZP + (size_t)b*(N+1) + r];
  float zn  = ws[OFF_ZN + (size_t)b*(N+1) + r];
  float zpT = ws[OFF_ZP + (size_t)b*(N+1) + N];
  float den = ep*(zpT - zp) + en*zn;
  ((int*)ws)[OFF_RNK + (size_t)b*N + i] = r;
  ws[OFF_C0 + (size_t)b*N + i] = ep/den;
  ws[OFF_C1 + (size_t)b*N + i] = en/den;
}

// --- R1: h_prime gather (+bf16 copy) -------------------------------------------
__global__ __launch_bounds__(256) void k_hprime2(float* __restrict__ ws,
                                                 ushort* __restrict__ hpb)
{
  int b = blockIdx.y, d = threadIdx.x;
  int i0 = blockIdx.x * 8;
  float totp = ws[OFF_PPOS + ((size_t)b*(N+1) + N)*D + d];
#pragma unroll
  for (int ii = 0; ii < 8; ++ii) {
    int i = i0 + ii;
    int   r  = ((const int*)ws)[OFF_RNK + (size_t)b*N + i];
    float c0 = ws[OFF_C0 + (size_t)b*N + i];
    float c1 = ws[OFF_C1 + (size_t)b*N + i];
    float pp = ws[OFF_PPOS + ((size_t)b*(N+1) + r)*D + d];
    float pn = ws[OFF_PNEG + ((size_t)b*(N+1) + r)*D + d];
    float v = c0*(totp - pp) + c1*pn;
    ws[OFF_HP + ((size_t)b*N + i)*D + d] = v;
    hpb[((size_t)b*N + i)*D + d] = f2bf(v);
  }
}

// --- logits: inv*(h'.kq + u.wq + c) ---------------------------------------------
__global__ __launch_bounds__(256) void k_logits(float* __restrict__ ws)
{
  int wid  = (int)(((size_t)blockIdx.x*256 + threadIdx.x) >> 6);
  int lane = threadIdx.x & 63;
  int d0 = lane << 2;
  int row0 = wid*4;
  int b = row0 >> 11;
  float4 kqe = *(const float4*)&ws[KQE + (size_t)b*D + d0];
  float4 wqe = *(const float4*)&ws[WQE + (size_t)b*D + d0];
  float4 kqa = *(const float4*)&ws[KQA + (size_t)b*D + d0];
  float4 wqa = *(const float4*)&ws[WQA + (size_t)b*D + d0];
  float ce = ws[CEc + b], ca = ws[CAc + b];
  for (int rr = 0; rr < 4; ++rr) {
    int row = row0 + rr;
    float4 hp = *(const float4*)&ws[OFF_HP + (size_t)row*D + d0];
    float4 ue = *(const float4*)&ws[OFF_UE + (size_t)row*D + d0];
    float4 ua = *(const float4*)&ws[OFF_UA + (size_t)row*D + d0];
    float se = hp.x*kqe.x + hp.y*kqe.y + hp.z*kqe.z + hp.w*kqe.w
             + ue.x*wqe.x + ue.y*wqe.y + ue.z*wqe.z + ue.w*wqe.w;
    float sa = hp.x*kqa.x + hp.y*kqa.y + hp.z*kqa.z + hp.w*kqa.w
             + ua.x*wqa.x + ua.y*wqa.y + ua.z*wqa.z + ua.w*wqa.w;
    se = wave_sum(se); sa = wave_sum(sa);
    if (lane == 0) {
      ws[OFF_LE + row] = (se + ce) * INVS;
      ws[OFF_LA + row] = (sa + ca) * INVS;
    }
  }
}

// --- probs softmax over N, writes directly to d_out -----------------------------
__global__ __launch_bounds__(1024) void k_softmax(const float* __restrict__ ws,
                                                  float* __restrict__ out)
{
  int b = blockIdx.x, t = threadIdx.x;
  __shared__ float red[1024];
  for (int m = 0; m < 2; ++m) {
    const float* l = ws + (m ? OFF_LA : OFF_LE) + (size_t)b*N;
    float* p = out + (size_t)B*N*D + (size_t)m*B*N + (size_t)b*N;
    float v0 = l[t], v1 = l[t + 1024];
    red[t] = fmaxf(v0, v1);
    __syncthreads();
    for (int s = 512; s > 0; s >>= 1) { if (t < s) red[t] = fmaxf(red[t], red[t+s]); __syncthreads(); }
    float mx = red[0];
    __syncthreads();
    float e0 = expf(v0 - mx), e1 = expf(v1 - mx);
    red[t] = e0 + e1;
    __syncthreads();
    for (int s = 512; s > 0; s >>= 1) { if (t < s) red[t] += red[t+s]; __syncthreads(); }
    float inv = 1.0f / red[0];
    __syncthreads();
    p[t] = e0 * inv; p[t + 1024] = e1 * inv;
    __syncthreads();
  }
}

// --- final: out = relu(h' + inp + pe*(qce+Ve) + pa*(qca+Va)) --------------------
__global__ __launch_bounds__(256) void k_final(
    const float* __restrict__ inp, const float* __restrict__ ws,
    float* __restrict__ out)
{
  size_t g = (size_t)blockIdx.x*256 + threadIdx.x;
  size_t base = g << 2;
  int b  = (int)(base >> 19);
  int n  = (int)((base >> 8) & (N - 1));
  int d0 = (int)(base & (D - 1));
  float pe = out[(size_t)B*N*D + (size_t)b*N + n];
  float pa = out[(size_t)B*N*D + (size_t)B*N + (size_t)b*N + n];
  float4 hp = *(const float4*)&ws[OFF_HP + base];
  float4 iv = *(const float4*)&inp[base];
  float4 ve = *(const float4*)&ws[OFF_VE + base];
  float4 va = *(const float4*)&ws[OFF_VA + base];
  float4 qe = *(const float4*)&ws[QCE + (size_t)b*D + d0];
  float4 qa = *(const float4*)&ws[QCA + (size_t)b*D + d0];
  float4 o;
  o.x = hp.x + iv.x + pe*(qe.x + ve.x) + pa*(qa.x + va.x);
  o.y = hp.y + iv.y + pe*(qe.y + ve.y) + pa*(qa.y + va.y);
  o.z = hp.z + iv.z + pe*(qe.z + ve.z) + pa*(qa.z + va.z);
  o.w = hp.w + iv.w + pe*(qe.w + ve.w) + pa*(qa.w + va.w);
  o.x = fmaxf(o.x, 0.f); o.y = fmaxf(o.y, 0.f);
  o.z = fmaxf(o.z, 0.f); o.w = fmaxf(o.w, 0.f);
  *(float4*)&out[base] = o;
}

extern "C" void kernel_launch(void* const* d_in, const int* in_sizes, int n_in,
                              void* d_out, int out_size, void* d_ws, size_t ws_size,
                              hipStream_t stream) {
  const float* inp  = (const float*)d_in[0];
  const float* emo  = (const float*)d_in[1];
  const float* bef  = (const float*)d_in[2];
  const float* aft  = (const float*)d_in[3];
  const float* ei   = (const float*)d_in[4];
  const float* eo   = (const float*)d_in[5];
  const float* ii   = (const float*)d_in[6];
  const float* io   = (const float*)d_in[7];
  const float* W    = (const float*)d_in[8];
  const float* a    = (const float*)d_in[9];
  const float* cskW = (const float*)d_in[10];
  const float* cskb = (const float*)d_in[11];
  const float* eW   = (const float*)d_in[12];
  const float* eb   = (const float*)d_in[13];
  const float* aW   = (const float*)d_in[14];
  const float* ab   = (const float*)d_in[15];
  const int*   cl   = (const int*)d_in[16];
  const int*   intra= (const int*)d_in[17];
  float* ws  = (float*)d_ws;
  float* out = (float*)d_out;
  ushort* ib  = (ushort*)(ws + OFF_IB);
  ushort* hpb = (ushort*)(ws + OFF_HPB);
  ushort* ueb = (ushort*)(ws + OFF_UEB);
  ushort* uab = (ushort*)(ws + OFF_UAB);
  ushort* bt  = (ushort*)(ws + OFF_BT);

  k_bt<<<dim3(16, 5), 256, 0, stream>>>(W, eW, aW, bt);
  k_cvt<<<1024, 256, 0, stream>>>(inp, ib);
  k_qpart<<<dim3(16, 2), 256, 0, stream>>>(inp, emo, eW, aW, cl, ws);
  k_mgemm<<<dim3(128, 2), 256, 0, stream>>>(ib, bt, nullptr, nullptr, ws + OFF_H);
  k_qfinish<<<dim3(B, 2), 256, 0, stream>>>(eb, ab, cskb, a, ws);
  k_u<<<2048, 256, 0, stream>>>(ei, eo, ii, io, cl, intra, ws, ueb, uab);
  k_rowdots<<<dim3(64, 17), 256, 0, stream>>>(eW, aW, cskW, a, ws);
  k_s12<<<512, 256, 0, stream>>>(bef, aft, a, ws);
  k_sort<<<B, 1024, 0, stream>>>(ws);
  k_rank<<<dim3(8, B), 256, 0, stream>>>(ws);
  k_p1<<<dim3(32, B), 256, 0, stream>>>(ws);
  k_p2<<<B, 256, 0, stream>>>(ws);
  k_p3<<<dim3(32, B), 256, 0, stream>>>(ws);
  k_hprime2<<<dim3(256, B), 256, 0, stream>>>(ws, hpb);
  k_mgemm<<<dim3(128, 2), 256, 0, stream>>>(hpb, bt + 1*65536, ueb, bt + 2*65536,
                                            ws + OFF_VE);
  k_mgemm<<<dim3(128, 2), 256, 0, stream>>>(hpb, bt + 3*65536, uab, bt + 4*65536,
                                            ws + OFF_VA);
  k_logits<<<512, 256, 0, stream>>>(ws);
  k_softmax<<<B, 1024, 0, stream>>>(ws, out);
  k_final<<<2048, 256, 0, stream>>>(inp, ws, out);
}